// Round 2
// baseline (222.286 us; speedup 1.0000x reference)
//
#include <hip/hip_runtime.h>
#include <math.h>

#define B 4
#define T 8
#define NF 8192
#define C 384
#define H 12
#define TOPK 32
#define D 32
#define STOT (T + NF)          // 8200
#define R (H * T)              // 96 score rows per batch
#define SCALE 0.17677669529663687f

typedef float f32x2 __attribute__((ext_vector_type(2)));

__device__ __forceinline__ void pkfma(f32x2& acc, f32x2 a, f32x2 b) {
  asm("v_pk_fma_f32 %0, %1, %2, %0" : "+v"(acc) : "v"(a), "v"(b));
}

// ---------------------------------------------------------------------------
// Kernel 1: per (b,t): q = x[b,t,:] @ qs_w[t], then fold k-projection:
// qk[h,c] = sum_d q[h*32+d] * kv_w[c, h*32+d]
// ---------------------------------------------------------------------------
__global__ __launch_bounds__(256) void ta_qk_kernel(
    const float* __restrict__ x, const float* __restrict__ qs_w,
    const float* __restrict__ kv_w, float* __restrict__ qk_buf) {
  int b = blockIdx.x / T, t = blockIdx.x % T;
  int tid = threadIdx.x;
  __shared__ float xrow[C];
  __shared__ float q[C];
  if (tid < C / 4) {
    *reinterpret_cast<float4*>(xrow + tid * 4) =
        *reinterpret_cast<const float4*>(x + ((size_t)b * STOT + t) * C + tid * 4);
  }
  __syncthreads();
  for (int o = tid; o < C; o += 256) {
    float acc = 0.f;
    const float* w = qs_w + (size_t)t * C * C + o;
    for (int c = 0; c < C; ++c) acc += xrow[c] * w[(size_t)c * C];
    q[o] = acc;
  }
  __syncthreads();
  for (int u = tid; u < H * C; u += 256) {
    int h = u / C, c = u % C;
    const float* kw = kv_w + (size_t)c * (2 * C) + h * D;
    const float* qh = q + h * D;
    float acc = 0.f;
#pragma unroll
    for (int d4 = 0; d4 < D / 4; ++d4) {
      float4 kv4 = *reinterpret_cast<const float4*>(kw + d4 * 4);
      acc += qh[d4 * 4 + 0] * kv4.x + qh[d4 * 4 + 1] * kv4.y +
             qh[d4 * 4 + 2] * kv4.z + qh[d4 * 4 + 3] * kv4.w;
    }
    qk_buf[((size_t)b * R + (size_t)h * T + t) * C + c] = acc;
  }
}

// ---------------------------------------------------------------------------
// Kernel 2: scores[(b*R + r)*NF + n] = SCALE * feat[b,n,:] . qk[b,r,:]
// 64n x 96r tile, KC=64, reg-prefetch pipeline, v_pk_fma_f32 (paired K).
// ---------------------------------------------------------------------------
#define TN 64
#define KC 64
__global__ __launch_bounds__(256, 2) void ta_scores_kernel(
    const float* __restrict__ x, const float* __restrict__ qk_buf,
    float* __restrict__ scores) {
  int b = blockIdx.y;
  int n0 = blockIdx.x * TN;
  int tid = threadIdx.x;
  int tr = tid & 15;   // n-group
  int tc = tid >> 4;   // r-group
  __shared__ float fA[TN][KC + 4];   // 17.4 KB
  __shared__ float fB[R][KC + 4];    // 26.1 KB
  f32x2 acc[4][6];
#pragma unroll
  for (int i = 0; i < 4; ++i)
#pragma unroll
    for (int j = 0; j < 6; ++j) acc[i][j] = (f32x2){0.f, 0.f};

  const float* xb = x + ((size_t)b * STOT + T + n0) * C;
  const float* qb = qk_buf + (size_t)b * R * C;

  float4 pa[4], pb[6];
#pragma unroll
  for (int s = 0; s < 4; ++s) {
    int v = tid + 256 * s, row = v >> 4, c4 = (v & 15) * 4;
    pa[s] = *reinterpret_cast<const float4*>(xb + (size_t)row * C + c4);
  }
#pragma unroll
  for (int s = 0; s < 6; ++s) {
    int v = tid + 256 * s, row = v >> 4, c4 = (v & 15) * 4;
    pb[s] = *reinterpret_cast<const float4*>(qb + (size_t)row * C + c4);
  }

#pragma unroll 1
  for (int c0 = 0; c0 < C; c0 += KC) {
    if (c0) __syncthreads();
#pragma unroll
    for (int s = 0; s < 4; ++s) {
      int v = tid + 256 * s, row = v >> 4, c4 = (v & 15) * 4;
      *reinterpret_cast<float4*>(&fA[row][c4]) = pa[s];
    }
#pragma unroll
    for (int s = 0; s < 6; ++s) {
      int v = tid + 256 * s, row = v >> 4, c4 = (v & 15) * 4;
      *reinterpret_cast<float4*>(&fB[row][c4]) = pb[s];
    }
    __syncthreads();
    if (c0 + KC < C) {  // prefetch next chunk; latency hides under compute
#pragma unroll
      for (int s = 0; s < 4; ++s) {
        int v = tid + 256 * s, row = v >> 4, c4 = (v & 15) * 4;
        pa[s] = *reinterpret_cast<const float4*>(xb + (size_t)row * C + c0 + KC + c4);
      }
#pragma unroll
      for (int s = 0; s < 6; ++s) {
        int v = tid + 256 * s, row = v >> 4, c4 = (v & 15) * 4;
        pb[s] = *reinterpret_cast<const float4*>(qb + (size_t)row * C + c0 + KC + c4);
      }
    }
#pragma unroll
    for (int kk = 0; kk < KC; kk += 4) {
      f32x2 a2[4][2], b2[6][2];
#pragma unroll
      for (int i = 0; i < 4; ++i) {
        a2[i][0] = *reinterpret_cast<const f32x2*>(&fA[tr + 16 * i][kk]);
        a2[i][1] = *reinterpret_cast<const f32x2*>(&fA[tr + 16 * i][kk + 2]);
      }
#pragma unroll
      for (int j = 0; j < 6; ++j) {
        b2[j][0] = *reinterpret_cast<const f32x2*>(&fB[tc + 16 * j][kk]);
        b2[j][1] = *reinterpret_cast<const f32x2*>(&fB[tc + 16 * j][kk + 2]);
      }
#pragma unroll
      for (int i = 0; i < 4; ++i)
#pragma unroll
        for (int j = 0; j < 6; ++j) {
          pkfma(acc[i][j], a2[i][0], b2[j][0]);
          pkfma(acc[i][j], a2[i][1], b2[j][1]);
        }
    }
  }
#pragma unroll
  for (int i = 0; i < 4; ++i) {
    int n = n0 + tr + 16 * i;
#pragma unroll
    for (int j = 0; j < 6; ++j) {
      int r = tc + 16 * j;
      scores[((size_t)b * R + r) * NF + n] = (acc[i][j].x + acc[i][j].y) * SCALE;
    }
  }
}

// ---------------------------------------------------------------------------
// Kernel 3: per score row: top-32 via hierarchical argmax (per-thread local max
// cached in registers; only the winning thread rescans its 32 elements).
// ---------------------------------------------------------------------------
__global__ __launch_bounds__(256) void ta_topk_kernel(
    const float* __restrict__ scores, float* __restrict__ w_buf,
    int* __restrict__ idx_buf) {
  int rr = blockIdx.x;
  int tid = threadIdx.x;
  const float* row = scores + (size_t)rr * NF;
  __shared__ float sv[NF];  // 32 KB
  __shared__ float wv[4];
  __shared__ int wi[4];
  __shared__ float selv[TOPK];
  __shared__ int seli[TOPK];
  __shared__ float eb[TOPK];
  __shared__ float esum;

  for (int i = tid * 4; i < NF; i += 1024)
    *reinterpret_cast<float4*>(sv + i) = *reinterpret_cast<const float4*>(row + i);
  __syncthreads();

  // per-thread local max over its contiguous 32 elements (rotated, bank-free)
  int base = tid << 5;
  float lmax = -1e30f;
  int li = base;
#pragma unroll 4
  for (int j = 0; j < 32; ++j) {
    int idx = base + ((j + tid) & 31);
    float v = sv[idx];
    if (v > lmax) { lmax = v; li = idx; }
  }

  int lane = tid & 63, wid = tid >> 6;
  for (int it = 0; it < TOPK; ++it) {
    float bv = lmax;
    int bi = li;
#pragma unroll
    for (int off = 32; off; off >>= 1) {
      float ov = __shfl_down(bv, off);
      int oi = __shfl_down(bi, off);
      if (ov > bv) { bv = ov; bi = oi; }
    }
    if (lane == 0) { wv[wid] = bv; wi[wid] = bi; }
    __syncthreads();
    if (tid == 0) {
      float mv = wv[0]; int mi = wi[0];
#pragma unroll
      for (int g = 1; g < 4; ++g)
        if (wv[g] > mv) { mv = wv[g]; mi = wi[g]; }
      selv[it] = mv; seli[it] = mi;
    }
    __syncthreads();
    int mi = seli[it];
    if ((mi >> 5) == tid) {  // owner invalidates + rescans its 32
      sv[mi] = -1e30f;
      lmax = -1e30f; li = base;
#pragma unroll 4
      for (int j = 0; j < 32; ++j) {
        int idx = base + ((j + tid) & 31);
        float v = sv[idx];
        if (v > lmax) { lmax = v; li = idx; }
      }
    }
  }
  if (tid < TOPK) eb[tid] = expf(selv[tid] - selv[0]);
  __syncthreads();
  if (tid == 0) {
    float s = 0.f;
    for (int k = 0; k < TOPK; ++k) s += eb[k];
    esum = s;
  }
  __syncthreads();
  if (tid < TOPK) {
    w_buf[(size_t)rr * TOPK + tid] = eb[tid] / esum;
    idx_buf[(size_t)rr * TOPK + tid] = seli[tid];
  }
}

// ---------------------------------------------------------------------------
// Kernel 4 (epilogue): grid = 96 r x 2 k-halves. Gather 16 feature rows to
// LDS (reused by v-compute and scatter); each thread caches its 32 ew column
// values in regs (reused 17x). v from kv_w via L2. All output via atomicAdd.
// ---------------------------------------------------------------------------
__global__ __launch_bounds__(256) void ta_epilogue_kernel(
    const float* __restrict__ x, const float* __restrict__ kv_w,
    const float* __restrict__ ew, const float* __restrict__ w_buf,
    const int* __restrict__ idx_buf, float* __restrict__ out) {
  constexpr int KH = TOPK / 2;  // 16
  int r = blockIdx.x >> 1, half = blockIdx.x & 1;
  int t = r % T, h = (r / T) % H, b = r / (H * T);
  int tid = threadIdx.x;
  __shared__ float F[KH][C + 4];   // 24.8 KB (pad: k-groups hit distinct banks)
  __shared__ float vS[KH][D];
  __shared__ float att[D];
  __shared__ float wl[KH];
  __shared__ int il[KH];

  if (tid < KH) {
    wl[tid] = w_buf[(size_t)r * TOPK + half * KH + tid];
    il[tid] = idx_buf[(size_t)r * TOPK + half * KH + tid];
  }
  __syncthreads();

  // register-cache my two ew columns (o = tid, tid+256)
  float ewc[2][D];
  const float* ewt = ew + (size_t)t * C * C + (size_t)h * D * C;
#pragma unroll
  for (int dd = 0; dd < D; ++dd) {
    ewc[0][dd] = ewt[(size_t)dd * C + tid];
    ewc[1][dd] = (tid < C - 256) ? ewt[(size_t)dd * C + tid + 256] : 0.f;
  }

  // gather the 16 selected feature rows
  for (int u = tid; u < KH * (C / 4); u += 256) {
    int krow = u / (C / 4);
    int e4 = (u - krow * (C / 4)) * 4;
    *reinterpret_cast<float4*>(&F[krow][e4]) =
        *reinterpret_cast<const float4*>(x + ((size_t)b * STOT + T + il[krow]) * C + e4);
  }
  __syncthreads();

  // v[k][d0..d0+1] = sum_c F[k][c] * kv_w[c, C + h*D + d0..]
  {
    int k = tid >> 4, d0 = (tid & 15) * 2;
    const float* kvp = kv_w + C + (size_t)h * D + d0;
    f32x2 s = {0.f, 0.f};
    for (int c4 = 0; c4 < C; c4 += 4) {
      float4 f4 = *reinterpret_cast<const float4*>(&F[k][c4]);
      f32x2 k0 = *reinterpret_cast<const f32x2*>(kvp + (size_t)(c4 + 0) * (2 * C));
      f32x2 k1 = *reinterpret_cast<const f32x2*>(kvp + (size_t)(c4 + 1) * (2 * C));
      f32x2 k2 = *reinterpret_cast<const f32x2*>(kvp + (size_t)(c4 + 2) * (2 * C));
      f32x2 k3 = *reinterpret_cast<const f32x2*>(kvp + (size_t)(c4 + 3) * (2 * C));
      s += (f32x2){f4.x, f4.x} * k0;
      s += (f32x2){f4.y, f4.y} * k1;
      s += (f32x2){f4.z, f4.z} * k2;
      s += (f32x2){f4.w, f4.w} * k3;
    }
    vS[k][d0] = s.x;
    vS[k][d0 + 1] = s.y;
  }
  __syncthreads();
  if (tid < D) {
    float a = 0.f;
#pragma unroll
    for (int k = 0; k < KH; ++k) a += wl[k] * vS[k][tid];
    att[tid] = a;
  }
  __syncthreads();

  // token contribution: att @ ew-slice
  {
    float a0 = 0.f, a1 = 0.f;
#pragma unroll
    for (int dd = 0; dd < D; ++dd) {
      float ad = att[dd];
      a0 += ad * ewc[0][dd];
      a1 += ad * ewc[1][dd];
    }
    float* trow = out + ((size_t)b * STOT + t) * C;
    atomicAdd(&trow[tid], a0);
    if (tid < C - 256) atomicAdd(&trow[tid + 256], a1);
  }
  // scatter: per k, out[b, T+il[k], :] += w_k * (F[k][hD:hD+32] @ ew-slice)
  for (int k = 0; k < KH; ++k) {
    float wk = wl[k];
    float fk[D];
#pragma unroll
    for (int d4 = 0; d4 < D; d4 += 4) {
      float4 f4 = *reinterpret_cast<const float4*>(&F[k][h * D + d4]);
      fk[d4] = f4.x; fk[d4 + 1] = f4.y; fk[d4 + 2] = f4.z; fk[d4 + 3] = f4.w;
    }
    float a0 = 0.f, a1 = 0.f;
#pragma unroll
    for (int dd = 0; dd < D; ++dd) {
      a0 += fk[dd] * ewc[0][dd];
      a1 += fk[dd] * ewc[1][dd];
    }
    float* orow = out + ((size_t)b * STOT + T + il[k]) * C;
    atomicAdd(&orow[tid], wk * a0);
    if (tid < C - 256) atomicAdd(&orow[tid + 256], wk * a1);
  }
}

// ---------------------------------------------------------------------------
extern "C" void kernel_launch(void* const* d_in, const int* in_sizes, int n_in,
                              void* d_out, int out_size, void* d_ws, size_t ws_size,
                              hipStream_t stream) {
  const float* x = (const float*)d_in[0];
  const float* qs_w = (const float*)d_in[1];
  const float* kv_w = (const float*)d_in[2];
  const float* ew = (const float*)d_in[3];
  float* out = (float*)d_out;

  float* qk_buf = (float*)d_ws;                       // B*R*C
  float* w_buf = qk_buf + (size_t)B * R * C;          // B*R*TOPK
  int* idx_buf = (int*)(w_buf + (size_t)B * R * TOPK);

  // scores (B*R*NF fp32 = 12.6 MB) staged inside d_out (50 MB), consumed by
  // top-k, then d_out is zeroed before the atomic epilogue.
  float* scores = out;

  ta_qk_kernel<<<B * T, 256, 0, stream>>>(x, qs_w, kv_w, qk_buf);
  dim3 g2(NF / TN, B);
  ta_scores_kernel<<<g2, 256, 0, stream>>>(x, qk_buf, scores);
  ta_topk_kernel<<<B * R, 256, 0, stream>>>(scores, w_buf, idx_buf);
  hipMemsetAsync(d_out, 0, (size_t)out_size * sizeof(float), stream);
  ta_epilogue_kernel<<<B * R * 2, 256, 0, stream>>>(x, kv_w, ew, w_buf, idx_buf, out);
}

// Round 3
// 180.060 us; speedup vs baseline: 1.2345x; 1.2345x over previous
//
#include <hip/hip_runtime.h>
#include <math.h>

#define B 4
#define T 8
#define NF 8192
#define C 384
#define H 12
#define TOPK 32
#define D 32
#define STOT (T + NF)          // 8200
#define R (H * T)              // 96 score rows per batch
#define SCALE 0.17677669529663687f

// ---------------------------------------------------------------------------
// Kernel 1: per (b,t), 384 threads: q[o] = x[b,t,:] @ qs_w[t] (thread = o,
// coalesced w loads), then fold k-projection: qk[h,c] = sum_d q[hD+d]*kv_w[c,hD+d]
// (thread = c, coalesced stores; kv row slice via float4).
// ---------------------------------------------------------------------------
__global__ __launch_bounds__(384) void ta_qk_kernel(
    const float* __restrict__ x, const float* __restrict__ qs_w,
    const float* __restrict__ kv_w, float* __restrict__ qk_buf) {
  int b = blockIdx.x / T, t = blockIdx.x % T;
  int tid = threadIdx.x;
  __shared__ float xrow[C];
  __shared__ float q[C];
  if (tid < C / 4) {
    *reinterpret_cast<float4*>(xrow + tid * 4) =
        *reinterpret_cast<const float4*>(x + ((size_t)b * STOT + t) * C + tid * 4);
  }
  __syncthreads();
  {
    const float* w = qs_w + (size_t)t * C * C + tid;
    float acc = 0.f;
#pragma unroll 8
    for (int c = 0; c < C; ++c) acc += xrow[c] * w[(size_t)c * C];
    q[tid] = acc;
  }
  __syncthreads();
  {
    const float* kr = kv_w + (size_t)tid * (2 * C);  // k-half of row c=tid
    float* qkb = qk_buf + (size_t)b * R * C;
#pragma unroll 1
    for (int h = 0; h < H; ++h) {
      float a = 0.f;
#pragma unroll
      for (int d4 = 0; d4 < D; d4 += 4) {
        float4 k4 = *reinterpret_cast<const float4*>(kr + h * D + d4);
        a += q[h * D + d4 + 0] * k4.x + q[h * D + d4 + 1] * k4.y +
             q[h * D + d4 + 2] * k4.z + q[h * D + d4 + 3] * k4.w;
      }
      qkb[((size_t)h * T + t) * C + tid] = a;
    }
  }
}

// ---------------------------------------------------------------------------
// Kernel 2 (R1 version, known-good 52us): scores = SCALE * feat . qk
// ---------------------------------------------------------------------------
#define TN 64
#define KC 32
__global__ __launch_bounds__(256) void ta_scores_kernel(
    const float* __restrict__ x, const float* __restrict__ qk_buf,
    float* __restrict__ scores) {
  int b = blockIdx.y;
  int n0 = blockIdx.x * TN;
  int tid = threadIdx.x;
  int tr = tid & 15;
  int tc = tid >> 4;
  __shared__ float fA[TN][KC + 4];
  __shared__ float fB[R][KC + 4];
  float acc[4][6];
#pragma unroll
  for (int i = 0; i < 4; ++i)
#pragma unroll
    for (int j = 0; j < 6; ++j) acc[i][j] = 0.f;

  const float* xb = x + ((size_t)b * STOT + T + n0) * C;
  const float* qb = qk_buf + (size_t)b * R * C;

  for (int c0 = 0; c0 < C; c0 += KC) {
#pragma unroll
    for (int s = 0; s < 2; ++s) {
      int v = tid + 256 * s;
      int row = v >> 3, c4 = (v & 7) * 4;
      float4 f = *reinterpret_cast<const float4*>(xb + (size_t)row * C + c0 + c4);
      *reinterpret_cast<float4*>(&fA[row][c4]) = f;
    }
#pragma unroll
    for (int s = 0; s < 3; ++s) {
      int v = tid + 256 * s;
      int row = v >> 3, c4 = (v & 7) * 4;
      float4 f = *reinterpret_cast<const float4*>(qb + (size_t)row * C + c0 + c4);
      *reinterpret_cast<float4*>(&fB[row][c4]) = f;
    }
    __syncthreads();
#pragma unroll
    for (int kk = 0; kk < KC; kk += 4) {
      float4 a4[4], b4[6];
#pragma unroll
      for (int i = 0; i < 4; ++i)
        a4[i] = *reinterpret_cast<const float4*>(&fA[tr + 16 * i][kk]);
#pragma unroll
      for (int j = 0; j < 6; ++j)
        b4[j] = *reinterpret_cast<const float4*>(&fB[tc + 16 * j][kk]);
#pragma unroll
      for (int i = 0; i < 4; ++i)
#pragma unroll
        for (int j = 0; j < 6; ++j) {
          acc[i][j] += a4[i].x * b4[j].x;
          acc[i][j] += a4[i].y * b4[j].y;
          acc[i][j] += a4[i].z * b4[j].z;
          acc[i][j] += a4[i].w * b4[j].w;
        }
    }
    __syncthreads();
  }
#pragma unroll
  for (int i = 0; i < 4; ++i) {
    int n = n0 + tr + 16 * i;
#pragma unroll
    for (int j = 0; j < 6; ++j) {
      int r = tc + 16 * j;
      scores[((size_t)b * R + r) * NF + n] = acc[i][j] * SCALE;
    }
  }
}

// ---------------------------------------------------------------------------
// Kernel 3: per score row: top-32 via hierarchical argmax + softmax.
// ---------------------------------------------------------------------------
__global__ __launch_bounds__(256) void ta_topk_kernel(
    const float* __restrict__ scores, float* __restrict__ w_buf,
    int* __restrict__ idx_buf) {
  int rr = blockIdx.x;
  int tid = threadIdx.x;
  const float* row = scores + (size_t)rr * NF;
  __shared__ float sv[NF];  // 32 KB
  __shared__ float wv[4];
  __shared__ int wi[4];
  __shared__ float selv[TOPK];
  __shared__ int seli[TOPK];
  __shared__ float eb[TOPK];
  __shared__ float esum;

  for (int i = tid * 4; i < NF; i += 1024)
    *reinterpret_cast<float4*>(sv + i) = *reinterpret_cast<const float4*>(row + i);
  __syncthreads();

  int base = tid << 5;
  float lmax = -1e30f;
  int li = base;
#pragma unroll 4
  for (int j = 0; j < 32; ++j) {
    int idx = base + ((j + tid) & 31);
    float v = sv[idx];
    if (v > lmax) { lmax = v; li = idx; }
  }

  int lane = tid & 63, wid = tid >> 6;
  for (int it = 0; it < TOPK; ++it) {
    float bv = lmax;
    int bi = li;
#pragma unroll
    for (int off = 32; off; off >>= 1) {
      float ov = __shfl_down(bv, off);
      int oi = __shfl_down(bi, off);
      if (ov > bv) { bv = ov; bi = oi; }
    }
    if (lane == 0) { wv[wid] = bv; wi[wid] = bi; }
    __syncthreads();
    if (tid == 0) {
      float mv = wv[0]; int mi = wi[0];
#pragma unroll
      for (int g = 1; g < 4; ++g)
        if (wv[g] > mv) { mv = wv[g]; mi = wi[g]; }
      selv[it] = mv; seli[it] = mi;
    }
    __syncthreads();
    int mi = seli[it];
    if ((mi >> 5) == tid) {
      sv[mi] = -1e30f;
      lmax = -1e30f; li = base;
#pragma unroll 4
      for (int j = 0; j < 32; ++j) {
        int idx = base + ((j + tid) & 31);
        float v = sv[idx];
        if (v > lmax) { lmax = v; li = idx; }
      }
    }
  }
  if (tid < TOPK) eb[tid] = expf(selv[tid] - selv[0]);
  __syncthreads();
  if (tid == 0) {
    float s = 0.f;
    for (int k = 0; k < TOPK; ++k) s += eb[k];
    esum = s;
  }
  __syncthreads();
  if (tid < TOPK) {
    w_buf[(size_t)rr * TOPK + tid] = eb[tid] / esum;
    idx_buf[(size_t)rr * TOPK + tid] = seli[tid];
  }
}

// ---------------------------------------------------------------------------
// Kernel 4: per (b,r,k-half): gather 16 feature rows to LDS, compute
// v[k][d] = F[k] . Vw[:,d] (Vw loads coalesced across d-lanes, L2-hot),
// emit g[k][d] = w_k * F[k][hD+d] and atomic-accumulate att[b,t,h,d].
// ---------------------------------------------------------------------------
__global__ __launch_bounds__(256) void ta_gv_kernel(
    const float* __restrict__ x, const float* __restrict__ kv_w,
    const float* __restrict__ w_buf, const int* __restrict__ idx_buf,
    float* __restrict__ g_buf, float* __restrict__ att_buf) {
  constexpr int KH = TOPK / 2;  // 16
  int br = blockIdx.x >> 1, half = blockIdx.x & 1;
  int t = br % T, h = (br / T) % H, b = br / (H * T);
  int tid = threadIdx.x;
  __shared__ float F[KH][C + 4];   // 24.8 KB
  __shared__ float part[8][D];
  __shared__ float wl[KH];
  __shared__ int il[KH];

  if (tid < KH) {
    wl[tid] = w_buf[(size_t)br * TOPK + half * KH + tid];
    il[tid] = idx_buf[(size_t)br * TOPK + half * KH + tid];
  }
  __syncthreads();
  for (int u = tid; u < KH * (C / 4); u += 256) {
    int k = u / (C / 4), e4 = (u % (C / 4)) * 4;
    *reinterpret_cast<float4*>(&F[k][e4]) =
        *reinterpret_cast<const float4*>(x + ((size_t)b * STOT + T + il[k]) * C + e4);
  }
  __syncthreads();

  int d = tid & 31, kg = tid >> 5;   // kg in 0..7
  int k0 = kg, k1 = kg + 8;
  const float* vw = kv_w + C + (size_t)h * D + d;
  float acc0 = 0.f, acc1 = 0.f;
#pragma unroll 4
  for (int c = 0; c < C; c += 4) {
    float w0 = vw[(size_t)(c + 0) * (2 * C)];
    float w1 = vw[(size_t)(c + 1) * (2 * C)];
    float w2 = vw[(size_t)(c + 2) * (2 * C)];
    float w3 = vw[(size_t)(c + 3) * (2 * C)];
    float4 f0 = *reinterpret_cast<const float4*>(&F[k0][c]);
    float4 f1 = *reinterpret_cast<const float4*>(&F[k1][c]);
    acc0 += f0.x * w0 + f0.y * w1 + f0.z * w2 + f0.w * w3;
    acc1 += f1.x * w0 + f1.y * w1 + f1.z * w2 + f1.w * w3;
  }
  // g vectors (w folded in)
  size_t gbase = ((size_t)br * TOPK + half * KH) * D;
  g_buf[gbase + (size_t)k0 * D + d] = wl[k0] * F[k0][h * D + d];
  g_buf[gbase + (size_t)k1 * D + d] = wl[k1] * F[k1][h * D + d];
  // att partial
  part[kg][d] = wl[k0] * acc0 + wl[k1] * acc1;
  __syncthreads();
  if (tid < D) {
    float s = 0.f;
#pragma unroll
    for (int g = 0; g < 8; ++g) s += part[g][tid];
    atomicAdd(&att_buf[(((size_t)b * T + t) * H + h) * D + tid], s);
  }
}

// ---------------------------------------------------------------------------
// Kernel 5: scatter. Block = (t,h,b), 384 threads (thread = output col o).
// ew columns register-cached (32 regs); per entry: 8 LDS broadcasts + 32 FMA
// + 1 atomicAdd. Token contribution added as a 33rd pseudo-entry.
// ---------------------------------------------------------------------------
__global__ __launch_bounds__(384) void ta_scatter_kernel(
    const float* __restrict__ ew, const float* __restrict__ g_buf,
    const float* __restrict__ att_buf, const int* __restrict__ idx_buf,
    float* __restrict__ out) {
  int grp = blockIdx.x >> 2, b = blockIdx.x & 3;
  int t = grp / H, h = grp % H;
  int br = b * R + h * T + t;
  int tid = threadIdx.x;  // = o
  __shared__ float gS[TOPK * D];   // 4 KB
  __shared__ float attS[D];
  __shared__ int ilS[TOPK];

  for (int u = tid; u < TOPK * D / 4; u += 384)
    *reinterpret_cast<float4*>(gS + u * 4) =
        *reinterpret_cast<const float4*>(g_buf + (size_t)br * TOPK * D + u * 4);
  if (tid < TOPK) ilS[tid] = idx_buf[(size_t)br * TOPK + tid];
  if (tid < D) attS[tid] = att_buf[(((size_t)b * T + t) * H + h) * D + tid];
  __syncthreads();

  // register-cache my ew column slice: ewc[dd] = ew[t, h*D+dd, o]
  float ewc[D];
  const float* ewt = ew + (size_t)t * C * C + (size_t)h * D * C + tid;
#pragma unroll
  for (int dd = 0; dd < D; ++dd) ewc[dd] = ewt[(size_t)dd * C];

  size_t orow_base = (size_t)b * STOT * C + tid;
#pragma unroll 1
  for (int k = 0; k < TOPK; ++k) {
    float y = 0.f;
#pragma unroll
    for (int d4 = 0; d4 < D; d4 += 4) {
      float4 g4 = *reinterpret_cast<const float4*>(gS + k * D + d4);
      y += g4.x * ewc[d4 + 0] + g4.y * ewc[d4 + 1] +
           g4.z * ewc[d4 + 2] + g4.w * ewc[d4 + 3];
    }
    atomicAdd(&out[orow_base + (size_t)(T + ilS[k]) * C], y);
  }
  {
    float y = 0.f;
#pragma unroll
    for (int d4 = 0; d4 < D; d4 += 4) {
      float4 a4 = *reinterpret_cast<const float4*>(attS + d4);
      y += a4.x * ewc[d4 + 0] + a4.y * ewc[d4 + 1] +
           a4.z * ewc[d4 + 2] + a4.w * ewc[d4 + 3];
    }
    atomicAdd(&out[orow_base + (size_t)t * C], y);
  }
}

// ---------------------------------------------------------------------------
extern "C" void kernel_launch(void* const* d_in, const int* in_sizes, int n_in,
                              void* d_out, int out_size, void* d_ws, size_t ws_size,
                              hipStream_t stream) {
  const float* x = (const float*)d_in[0];
  const float* qs_w = (const float*)d_in[1];
  const float* kv_w = (const float*)d_in[2];
  const float* ew = (const float*)d_in[3];
  float* out = (float*)d_out;

  // ws layout (floats): qk_buf[B*R*C] | w_buf[B*R*K] | idx_buf[B*R*K] |
  //                     g_buf[B*R*K*D] | att_buf[B*T*H*D]
  float* qk_buf = (float*)d_ws;
  float* w_buf = qk_buf + (size_t)B * R * C;
  int* idx_buf = (int*)(w_buf + (size_t)B * R * TOPK);
  float* g_buf = (float*)(idx_buf + (size_t)B * R * TOPK);
  float* att_buf = g_buf + (size_t)B * R * TOPK * D;

  // scores (12.6 MB) staged inside d_out (50 MB), consumed by top-k before
  // d_out is zeroed for the atomic epilogue.
  float* scores = out;

  ta_qk_kernel<<<B * T, 384, 0, stream>>>(x, qs_w, kv_w, qk_buf);
  dim3 g2(NF / TN, B);
  ta_scores_kernel<<<g2, 256, 0, stream>>>(x, qk_buf, scores);
  ta_topk_kernel<<<B * R, 256, 0, stream>>>(scores, w_buf, idx_buf);
  hipMemsetAsync(d_out, 0, (size_t)out_size * sizeof(float), stream);
  hipMemsetAsync(att_buf, 0, (size_t)B * T * H * D * sizeof(float), stream);
  ta_gv_kernel<<<B * R * 2, 256, 0, stream>>>(x, kv_w, w_buf, idx_buf, g_buf, att_buf);
  ta_scatter_kernel<<<T * H * B, 384, 0, stream>>>(ew, g_buf, att_buf, idx_buf, out);
}

// Round 4
// 145.197 us; speedup vs baseline: 1.5309x; 1.2401x over previous
//
#include <hip/hip_runtime.h>
#include <math.h>

#define B 4
#define T 8
#define NF 8192
#define C 384
#define H 12
#define TOPK 32
#define D 32
#define STOT (T + NF)          // 8200
#define R (H * T)              // 96 score rows per batch
#define KSEL 48                // selection margin (bf16 scores -> exact rescore)
#define SCALE 0.17677669529663687f

typedef unsigned int uint;
typedef unsigned short ushort;
typedef short bf16x8 __attribute__((ext_vector_type(8)));
typedef float f32x4 __attribute__((ext_vector_type(4)));

__device__ __forceinline__ uint pk_bf16(float a, float b) {
  uint ua = __builtin_bit_cast(uint, a);
  uint ub = __builtin_bit_cast(uint, b);
  ua = (ua + 0x7FFFu + ((ua >> 16) & 1u)) >> 16;
  ub = (ub + 0x7FFFu + ((ub >> 16) & 1u)) >> 16;
  return ua | (ub << 16);
}

// ---------------------------------------------------------------------------
// Kernel 1: per (b,t), 384 threads: q = x[b,t,:] @ qs_w[t]; fold k-proj:
// qk[h,c] = sum_d q[hD+d]*kv_w[c,hD+d]. Emits qk in f32 (rescore) + bf16 (MFMA).
// ---------------------------------------------------------------------------
__global__ __launch_bounds__(384) void ta_qk_kernel(
    const float* __restrict__ x, const float* __restrict__ qs_w,
    const float* __restrict__ kv_w, float* __restrict__ qk_f32,
    ushort* __restrict__ qk_bf) {
  int b = blockIdx.x / T, t = blockIdx.x % T;
  int tid = threadIdx.x;
  __shared__ float xrow[C];
  __shared__ float q[C];
  if (tid < C / 4) {
    *reinterpret_cast<float4*>(xrow + tid * 4) =
        *reinterpret_cast<const float4*>(x + ((size_t)b * STOT + t) * C + tid * 4);
  }
  __syncthreads();
  {
    const float* w = qs_w + (size_t)t * C * C + tid;
    float acc = 0.f;
#pragma unroll 8
    for (int c = 0; c < C; ++c) acc += xrow[c] * w[(size_t)c * C];
    q[tid] = acc;
  }
  __syncthreads();
  {
    const float* kr = kv_w + (size_t)tid * (2 * C);  // k-half of row c=tid
#pragma unroll 1
    for (int h = 0; h < H; ++h) {
      float a = 0.f;
#pragma unroll
      for (int d4 = 0; d4 < D; d4 += 4) {
        float4 k4 = *reinterpret_cast<const float4*>(kr + h * D + d4);
        a += q[h * D + d4 + 0] * k4.x + q[h * D + d4 + 1] * k4.y +
             q[h * D + d4 + 2] * k4.z + q[h * D + d4 + 3] * k4.w;
      }
      size_t off = ((size_t)b * R + (size_t)h * T + t) * C + tid;
      qk_f32[off] = a;
      uint ua = __builtin_bit_cast(uint, a);
      qk_bf[off] = (ushort)((ua + 0x7FFFu + ((ua >> 16) & 1u)) >> 16);
    }
  }
}

// ---------------------------------------------------------------------------
// Kernel 2: bf16 MFMA scores. Block = 64 n-cols x all 96 r, 4 waves (16n each).
// K=384 in 12 chunks of 32. feat converted f32->bf16 during LDS staging.
// scores[b][r][n] fp32 (selection only; exact values recomputed in rescore).
// ---------------------------------------------------------------------------
__global__ __launch_bounds__(256) void ta_scores_kernel(
    const float* __restrict__ x, const ushort* __restrict__ qk_bf,
    float* __restrict__ scores) {
  int b = blockIdx.y;
  int n0 = blockIdx.x * 64;
  int tid = threadIdx.x;
  int lane = tid & 63, w = tid >> 6;
  int row16 = lane & 15, kg = lane >> 4;  // k-group 0..3 -> k_off = kg*8
  __shared__ ushort fS[64][72];  // feat bf16, padded (72) for bank spread
  __shared__ ushort qS[96][72];  // qk bf16
  f32x4 acc[6];
#pragma unroll
  for (int i = 0; i < 6; ++i) acc[i] = (f32x4){0.f, 0.f, 0.f, 0.f};

  const float* xb = x + ((size_t)b * STOT + T + n0) * C;
  const ushort* qb = qk_bf + (size_t)b * R * C;

  int frow = tid >> 2, fcg = (tid & 3) * 8;  // feat stage: row 0..63, col grp

#pragma unroll 1
  for (int c0 = 0; c0 < C; c0 += 32) {
    // stage feat tile (64 x 32 f32 -> bf16)
    {
      const float* src = xb + (size_t)frow * C + c0 + fcg;
      float4 v0 = *reinterpret_cast<const float4*>(src);
      float4 v1 = *reinterpret_cast<const float4*>(src + 4);
      uint4 p;
      p.x = pk_bf16(v0.x, v0.y);
      p.y = pk_bf16(v0.z, v0.w);
      p.z = pk_bf16(v1.x, v1.y);
      p.w = pk_bf16(v1.z, v1.w);
      *reinterpret_cast<uint4*>(&fS[frow][fcg]) = p;
    }
    // stage qk tile (96 x 32 bf16): 384 16B jobs
#pragma unroll
    for (int s = 0; s < 2; ++s) {
      int u = tid + 256 * s;
      if (u < 384) {
        int row = u >> 2, cg = (u & 3) * 8;
        uint4 v = *reinterpret_cast<const uint4*>(qb + (size_t)row * C + c0 + cg);
        *reinterpret_cast<uint4*>(&qS[row][cg]) = v;
      }
    }
    __syncthreads();
    bf16x8 bfr = *reinterpret_cast<const bf16x8*>(&fS[w * 16 + row16][kg * 8]);
#pragma unroll
    for (int i = 0; i < 6; ++i) {
      bf16x8 afr = *reinterpret_cast<const bf16x8*>(&qS[i * 16 + row16][kg * 8]);
      acc[i] = __builtin_amdgcn_mfma_f32_16x16x32_bf16(afr, bfr, acc[i], 0, 0, 0);
    }
    __syncthreads();
  }
  int n = n0 + w * 16 + row16;
#pragma unroll
  for (int i = 0; i < 6; ++i) {
    int rbase = i * 16 + kg * 4;
#pragma unroll
    for (int reg = 0; reg < 4; ++reg) {
      scores[((size_t)b * R + rbase + reg) * NF + n] = acc[i][reg] * SCALE;
    }
  }
}

// ---------------------------------------------------------------------------
// Kernel 3: exact radix-select of top-KSEL per row. 4x 8-bit passes on
// sign-flipped uint keys find the exact 48th value; collection pass emits the
// candidate set (ties -> ascending index, matching lax.top_k).
// ---------------------------------------------------------------------------
__global__ __launch_bounds__(256) void ta_select_kernel(
    const float* __restrict__ scores, int* __restrict__ cand) {
  int rr = blockIdx.x;
  int tid = threadIdx.x;
  const float* rowp = scores + (size_t)rr * NF;
  __shared__ uint su[NF];      // 32 KB keys
  __shared__ uint hist[256];
  __shared__ uint cum[256];
  __shared__ uint prefix, above, cgt, ceq;
  __shared__ int gt_list[KSEL];
  __shared__ uint eq_list[64];

  for (int i = tid * 4; i < NF; i += 1024) {
    float4 v = *reinterpret_cast<const float4*>(rowp + i);
    uint u0 = __builtin_bit_cast(uint, v.x);
    uint u1 = __builtin_bit_cast(uint, v.y);
    uint u2 = __builtin_bit_cast(uint, v.z);
    uint u3 = __builtin_bit_cast(uint, v.w);
    su[i + 0] = u0 ^ (uint)(((int)u0 >> 31) | 0x80000000);
    su[i + 1] = u1 ^ (uint)(((int)u1 >> 31) | 0x80000000);
    su[i + 2] = u2 ^ (uint)(((int)u2 >> 31) | 0x80000000);
    su[i + 3] = u3 ^ (uint)(((int)u3 >> 31) | 0x80000000);
  }
  if (tid == 0) { prefix = 0; above = 0; cgt = 0; ceq = 0; }
  __syncthreads();

#pragma unroll 1
  for (int p = 0; p < 4; ++p) {
    int sh = 24 - 8 * p;
    hist[tid] = 0;
    __syncthreads();
    uint pref = prefix;
    uint ab = above;
    for (int i = tid; i < NF; i += 256) {
      uint u = su[i];
      if (p == 0 || (u >> (sh + 8)) == pref)
        atomicAdd(&hist[(u >> sh) & 255], 1u);
    }
    __syncthreads();
    cum[tid] = hist[tid];
    __syncthreads();
#pragma unroll
    for (int off = 1; off < 256; off <<= 1) {
      uint add = (tid + off < 256) ? cum[tid + off] : 0;
      __syncthreads();
      cum[tid] += add;
      __syncthreads();
    }
    uint need = (uint)(KSEL)-ab;
    uint total_ge = cum[tid];
    uint ge_next = (tid < 255) ? cum[tid + 1] : 0;
    if (total_ge >= need && ge_next < need) {
      prefix = (pref << 8) | (uint)tid;
      above = ab + ge_next;
    }
    __syncthreads();
  }

  uint piv = prefix;
  uint ab = above;           // count of u > piv, < KSEL
  for (int i = tid; i < NF; i += 256) {
    uint u = su[i];
    if (u > piv) {
      uint s = atomicAdd(&cgt, 1u);
      gt_list[s] = i;
    } else if (u == piv) {
      uint s = atomicAdd(&ceq, 1u);
      if (s < 64) eq_list[s] = (uint)i;
    }
  }
  __syncthreads();
  if (tid < (int)ab) cand[(size_t)rr * KSEL + tid] = gt_list[tid];
  uint ne = ceq < 64u ? ceq : 64u;
  if (tid < (int)ne) {
    uint my = eq_list[tid];
    int rk = 0;
    for (uint e = 0; e < ne; ++e) rk += (eq_list[e] < my);
    if (rk < (int)(KSEL - ab)) cand[(size_t)rr * KSEL + ab + rk] = (int)my;
  }
}

// ---------------------------------------------------------------------------
// Kernel 4: exact fp32 rescore of 48 candidates, rank -> true top-32 + softmax.
// 384 threads: 8 per candidate.
// ---------------------------------------------------------------------------
__global__ __launch_bounds__(384) void ta_rescore_kernel(
    const float* __restrict__ x, const float* __restrict__ qk_f32,
    const int* __restrict__ cand, float* __restrict__ w_buf,
    int* __restrict__ idx_buf) {
  int rr = blockIdx.x;
  int b = rr / R;
  int tid = threadIdx.x;
  __shared__ float qS[C];
  __shared__ int il[KSEL];
  __shared__ float sv[KSEL];
  __shared__ int rk[KSEL];
  __shared__ float smax, esum;
  qS[tid] = qk_f32[(size_t)rr * C + tid];
  if (tid < KSEL) il[tid] = cand[(size_t)rr * KSEL + tid];
  __syncthreads();
  int k = tid >> 3, j = tid & 7;
  const float* fp = x + ((size_t)b * STOT + T + il[k]) * C + j;
  float s = 0.f;
#pragma unroll 8
  for (int m = 0; m < 48; ++m) s += fp[m * 8] * qS[j + m * 8];
  s += __shfl_down(s, 4);
  s += __shfl_down(s, 2);
  s += __shfl_down(s, 1);
  if (j == 0) sv[k] = s * SCALE;
  __syncthreads();
  if (tid < KSEL) {
    float mys = sv[tid];
    int myn = il[tid];
    int r = 0;
#pragma unroll
    for (int e = 0; e < KSEL; ++e) {
      float se = sv[e];
      r += (se > mys) || (se == mys && il[e] < myn);
    }
    rk[tid] = r;
    if (r == 0) smax = mys;
  }
  __syncthreads();
  float e = 0.f;
  if (tid < KSEL && rk[tid] < TOPK) e = expf(sv[tid] - smax);
  if (tid < 64) {
    float t2 = e;
#pragma unroll
    for (int off = 32; off; off >>= 1) t2 += __shfl_down(t2, off);
    if (tid == 0) esum = t2;
  }
  __syncthreads();
  if (tid < KSEL && rk[tid] < TOPK) {
    w_buf[(size_t)rr * TOPK + rk[tid]] = e / esum;
    idx_buf[(size_t)rr * TOPK + rk[tid]] = il[tid];
  }
}

// ---------------------------------------------------------------------------
// Kernel 5: per (b,r,k-half): gather 16 feature rows to LDS, v = F . Vw,
// g[k][d] = w_k * F[k][hD+d], atomic-accumulate att[b,t,h,d].
// ---------------------------------------------------------------------------
__global__ __launch_bounds__(256) void ta_gv_kernel(
    const float* __restrict__ x, const float* __restrict__ kv_w,
    const float* __restrict__ w_buf, const int* __restrict__ idx_buf,
    float* __restrict__ g_buf, float* __restrict__ att_buf) {
  constexpr int KH = TOPK / 2;  // 16
  int br = blockIdx.x >> 1, half = blockIdx.x & 1;
  int t = br % T, h = (br / T) % H, b = br / (H * T);
  int tid = threadIdx.x;
  __shared__ float F[KH][C + 4];
  __shared__ float part[8][D];
  __shared__ float wl[KH];
  __shared__ int il[KH];

  if (tid < KH) {
    wl[tid] = w_buf[(size_t)br * TOPK + half * KH + tid];
    il[tid] = idx_buf[(size_t)br * TOPK + half * KH + tid];
  }
  __syncthreads();
  for (int u = tid; u < KH * (C / 4); u += 256) {
    int k = u / (C / 4), e4 = (u % (C / 4)) * 4;
    *reinterpret_cast<float4*>(&F[k][e4]) =
        *reinterpret_cast<const float4*>(x + ((size_t)b * STOT + T + il[k]) * C + e4);
  }
  __syncthreads();

  int d = tid & 31, kg = tid >> 5;
  int k0 = kg, k1 = kg + 8;
  const float* vw = kv_w + C + (size_t)h * D + d;
  float acc0 = 0.f, acc1 = 0.f;
#pragma unroll 4
  for (int c = 0; c < C; c += 4) {
    float w0 = vw[(size_t)(c + 0) * (2 * C)];
    float w1 = vw[(size_t)(c + 1) * (2 * C)];
    float w2 = vw[(size_t)(c + 2) * (2 * C)];
    float w3 = vw[(size_t)(c + 3) * (2 * C)];
    float4 f0 = *reinterpret_cast<const float4*>(&F[k0][c]);
    float4 f1 = *reinterpret_cast<const float4*>(&F[k1][c]);
    acc0 += f0.x * w0 + f0.y * w1 + f0.z * w2 + f0.w * w3;
    acc1 += f1.x * w0 + f1.y * w1 + f1.z * w2 + f1.w * w3;
  }
  size_t gbase = ((size_t)br * TOPK + half * KH) * D;
  g_buf[gbase + (size_t)k0 * D + d] = wl[k0] * F[k0][h * D + d];
  g_buf[gbase + (size_t)k1 * D + d] = wl[k1] * F[k1][h * D + d];
  part[kg][d] = wl[k0] * acc0 + wl[k1] * acc1;
  __syncthreads();
  if (tid < D) {
    float s = 0.f;
#pragma unroll
    for (int g = 0; g < 8; ++g) s += part[g][tid];
    atomicAdd(&att_buf[(((size_t)b * T + t) * H + h) * D + tid], s);
  }
}

// ---------------------------------------------------------------------------
// Kernel 6: scatter. Block = (t,h,b), 384 threads (thread = output col o).
// ---------------------------------------------------------------------------
__global__ __launch_bounds__(384) void ta_scatter_kernel(
    const float* __restrict__ ew, const float* __restrict__ g_buf,
    const float* __restrict__ att_buf, const int* __restrict__ idx_buf,
    float* __restrict__ out) {
  int grp = blockIdx.x >> 2, b = blockIdx.x & 3;
  int t = grp / H, h = grp % H;
  int br = b * R + h * T + t;
  int tid = threadIdx.x;  // = o
  __shared__ float gS[TOPK * D];
  __shared__ float attS[D];
  __shared__ int ilS[TOPK];

  for (int u = tid; u < TOPK * D / 4; u += 384)
    *reinterpret_cast<float4*>(gS + u * 4) =
        *reinterpret_cast<const float4*>(g_buf + (size_t)br * TOPK * D + u * 4);
  if (tid < TOPK) ilS[tid] = idx_buf[(size_t)br * TOPK + tid];
  if (tid < D) attS[tid] = att_buf[(((size_t)b * T + t) * H + h) * D + tid];
  __syncthreads();

  float ewc[D];
  const float* ewt = ew + (size_t)t * C * C + (size_t)h * D * C + tid;
#pragma unroll
  for (int dd = 0; dd < D; ++dd) ewc[dd] = ewt[(size_t)dd * C];

  size_t orow_base = (size_t)b * STOT * C + tid;
#pragma unroll 1
  for (int k = 0; k < TOPK; ++k) {
    float y = 0.f;
#pragma unroll
    for (int d4 = 0; d4 < D; d4 += 4) {
      float4 g4 = *reinterpret_cast<const float4*>(gS + k * D + d4);
      y += g4.x * ewc[d4 + 0] + g4.y * ewc[d4 + 1] +
           g4.z * ewc[d4 + 2] + g4.w * ewc[d4 + 3];
    }
    atomicAdd(&out[orow_base + (size_t)(T + ilS[k]) * C], y);
  }
  {
    float y = 0.f;
#pragma unroll
    for (int d4 = 0; d4 < D; d4 += 4) {
      float4 a4 = *reinterpret_cast<const float4*>(attS + d4);
      y += a4.x * ewc[d4 + 0] + a4.y * ewc[d4 + 1] +
           a4.z * ewc[d4 + 2] + a4.w * ewc[d4 + 3];
    }
    atomicAdd(&out[orow_base + (size_t)t * C], y);
  }
}

// ---------------------------------------------------------------------------
extern "C" void kernel_launch(void* const* d_in, const int* in_sizes, int n_in,
                              void* d_out, int out_size, void* d_ws, size_t ws_size,
                              hipStream_t stream) {
  const float* x = (const float*)d_in[0];
  const float* qs_w = (const float*)d_in[1];
  const float* kv_w = (const float*)d_in[2];
  const float* ew = (const float*)d_in[3];
  float* out = (float*)d_out;

  // ws layout (bytes, all 16B-aligned):
  char* p = (char*)d_ws;
  float* qk_f32 = (float*)p;               p += (size_t)B * R * C * 4;       // 589824
  ushort* qk_bf = (ushort*)p;              p += (size_t)B * R * C * 2;       // 294912
  int* cand = (int*)p;                     p += (size_t)B * R * KSEL * 4;    // 73728
  float* w_buf = (float*)p;                p += (size_t)B * R * TOPK * 4;    // 49152
  int* idx_buf = (int*)p;                  p += (size_t)B * R * TOPK * 4;    // 49152
  float* g_buf = (float*)p;                p += (size_t)B * R * TOPK * D * 4;// 1572864
  float* att_buf = (float*)p;

  // scores (B*R*NF fp32 = 12.58M floats) staged inside d_out (12.59M floats),
  // fully consumed by ta_select before d_out is zeroed.
  float* scores = out;

  ta_qk_kernel<<<B * T, 384, 0, stream>>>(x, qs_w, kv_w, qk_f32, qk_bf);
  dim3 g2(NF / 64, B);
  ta_scores_kernel<<<g2, 256, 0, stream>>>(x, qk_bf, scores);
  ta_select_kernel<<<B * R, 256, 0, stream>>>(scores, cand);
  ta_rescore_kernel<<<B * R, 384, 0, stream>>>(x, qk_f32, cand, w_buf, idx_buf);
  hipMemsetAsync(d_out, 0, (size_t)out_size * sizeof(float), stream);
  hipMemsetAsync(att_buf, 0, (size_t)B * T * H * D * sizeof(float), stream);
  ta_gv_kernel<<<B * R * 2, 256, 0, stream>>>(x, kv_w, w_buf, idx_buf, g_buf, att_buf);
  ta_scatter_kernel<<<T * H * B, 384, 0, stream>>>(ew, g_buf, att_buf, idx_buf, out);
}

// Round 5
// 119.316 us; speedup vs baseline: 1.8630x; 1.2169x over previous
//
#include <hip/hip_runtime.h>
#include <math.h>

#define B 4
#define T 8
#define NF 8192
#define C 384
#define H 12
#define TOPK 32
#define D 32
#define STOT (T + NF)          // 8200
#define R (H * T)              // 96 score rows per batch
#define KSEL 48                // selection margin (bf16 scores -> exact rescore)
#define SCALE 0.17677669529663687f

typedef unsigned int uint;
typedef unsigned short ushort;
typedef short bf16x8 __attribute__((ext_vector_type(8)));
typedef float f32x4 __attribute__((ext_vector_type(4)));

__device__ __forceinline__ uint pk_bf16(float a, float b) {
  uint ua = __builtin_bit_cast(uint, a);
  uint ub = __builtin_bit_cast(uint, b);
  ua = (ua + 0x7FFFu + ((ua >> 16) & 1u)) >> 16;
  ub = (ub + 0x7FFFu + ((ub >> 16) & 1u)) >> 16;
  return ua | (ub << 16);
}

// ---------------------------------------------------------------------------
// Kernel 0: LDS-tiled transpose of kv_w k-half: kT[j][c] = kv_w[c][j], j<C.
// ---------------------------------------------------------------------------
__global__ __launch_bounds__(256) void ta_transpose_kernel(
    const float* __restrict__ kv_w, float* __restrict__ kT) {
  int j0 = blockIdx.x * 32, c0 = blockIdx.y * 32;
  int tid = threadIdx.x;
  __shared__ float tile[32][33];
  {
    int cc = tid >> 3, j4 = (tid & 7) * 4;
    float4 v = *reinterpret_cast<const float4*>(
        kv_w + (size_t)(c0 + cc) * (2 * C) + j0 + j4);
    tile[cc][j4 + 0] = v.x; tile[cc][j4 + 1] = v.y;
    tile[cc][j4 + 2] = v.z; tile[cc][j4 + 3] = v.w;
  }
  __syncthreads();
  {
    int jj = tid >> 3, c4 = (tid & 7) * 4;
    float4 v;
    v.x = tile[c4 + 0][jj]; v.y = tile[c4 + 1][jj];
    v.z = tile[c4 + 2][jj]; v.w = tile[c4 + 3][jj];
    *reinterpret_cast<float4*>(kT + (size_t)(j0 + jj) * C + c0 + c4) = v;
  }
}

// ---------------------------------------------------------------------------
// Kernel 1a: q-projection. grid (T, 6 o-tiles, 2 k-halves), 256 thr =
// 64 o x 4 ks (48 c each). All B batches per thread. q_part[z][b][t][o].
// ---------------------------------------------------------------------------
__global__ __launch_bounds__(256) void ta_qproj_kernel(
    const float* __restrict__ x, const float* __restrict__ qs_w,
    float* __restrict__ q_part) {
  int t = blockIdx.x;
  int o0 = blockIdx.y * 64;
  int z = blockIdx.z;
  int tid = threadIdx.x;
  int o = tid & 63, ks = tid >> 6;
  __shared__ float xs[B][192];
  __shared__ float part[4][B][64];
  if (tid < 192) {
    int b = tid / 48, j4 = (tid % 48) * 4;
    *reinterpret_cast<float4*>(&xs[b][j4]) =
        *reinterpret_cast<const float4*>(x + ((size_t)b * STOT + t) * C + z * 192 + j4);
  }
  __syncthreads();
  float a0 = 0.f, a1 = 0.f, a2 = 0.f, a3 = 0.f;
  const float* w = qs_w + (size_t)t * C * C + (size_t)(z * 192 + ks * 48) * C + o0 + o;
#pragma unroll 8
  for (int c = 0; c < 48; ++c) {
    float wv = w[(size_t)c * C];
    int cj = ks * 48 + c;
    a0 += xs[0][cj] * wv;
    a1 += xs[1][cj] * wv;
    a2 += xs[2][cj] * wv;
    a3 += xs[3][cj] * wv;
  }
  part[ks][0][o] = a0; part[ks][1][o] = a1;
  part[ks][2][o] = a2; part[ks][3][o] = a3;
  __syncthreads();
  {
    int b = tid >> 6, oo = tid & 63;
    float s = part[0][b][oo] + part[1][b][oo] + part[2][b][oo] + part[3][b][oo];
    q_part[(((size_t)z * B + b) * T + t) * C + o0 + oo] = s;
  }
}

// ---------------------------------------------------------------------------
// Kernel 1b: fold k-projection. grid = B*H, 384 thr (thread = c):
// qk[b,hT+t,c] = sum_d qh[t][d] * kT[hD+d][c]. Coalesced kT reads.
// ---------------------------------------------------------------------------
__global__ __launch_bounds__(384) void ta_fold_kernel(
    const float* __restrict__ q_part, const float* __restrict__ kT,
    float* __restrict__ qk_f32, ushort* __restrict__ qk_bf) {
  int b = blockIdx.x / H, h = blockIdx.x % H;
  int tid = threadIdx.x;
  __shared__ float qh[T][D];
  if (tid < T * D) {
    int t = tid >> 5, d = tid & 31;
    qh[t][d] = q_part[((size_t)b * T + t) * C + h * D + d] +
               q_part[(((size_t)B + b) * T + t) * C + h * D + d];
  }
  __syncthreads();
  float acc[T] = {0.f, 0.f, 0.f, 0.f, 0.f, 0.f, 0.f, 0.f};
#pragma unroll
  for (int d = 0; d < D; ++d) {
    float kv = kT[(size_t)(h * D + d) * C + tid];
#pragma unroll
    for (int t = 0; t < T; ++t) acc[t] += qh[t][d] * kv;
  }
#pragma unroll
  for (int t = 0; t < T; ++t) {
    size_t off = ((size_t)b * R + (size_t)h * T + t) * C + tid;
    float a = acc[t];
    qk_f32[off] = a;
    uint ua = __builtin_bit_cast(uint, a);
    qk_bf[off] = (ushort)((ua + 0x7FFFu + ((ua >> 16) & 1u)) >> 16);
  }
}

// ---------------------------------------------------------------------------
// Kernel 2: bf16 MFMA scores. Block = 64 n-cols x all 96 r, 4 waves.
// ---------------------------------------------------------------------------
__global__ __launch_bounds__(256) void ta_scores_kernel(
    const float* __restrict__ x, const ushort* __restrict__ qk_bf,
    float* __restrict__ scores) {
  int b = blockIdx.y;
  int n0 = blockIdx.x * 64;
  int tid = threadIdx.x;
  int lane = tid & 63, w = tid >> 6;
  int row16 = lane & 15, kg = lane >> 4;
  __shared__ ushort fS[64][72];
  __shared__ ushort qS[96][72];
  f32x4 acc[6];
#pragma unroll
  for (int i = 0; i < 6; ++i) acc[i] = (f32x4){0.f, 0.f, 0.f, 0.f};

  const float* xb = x + ((size_t)b * STOT + T + n0) * C;
  const ushort* qb = qk_bf + (size_t)b * R * C;

  int frow = tid >> 2, fcg = (tid & 3) * 8;

#pragma unroll 1
  for (int c0 = 0; c0 < C; c0 += 32) {
    {
      const float* src = xb + (size_t)frow * C + c0 + fcg;
      float4 v0 = *reinterpret_cast<const float4*>(src);
      float4 v1 = *reinterpret_cast<const float4*>(src + 4);
      uint4 p;
      p.x = pk_bf16(v0.x, v0.y);
      p.y = pk_bf16(v0.z, v0.w);
      p.z = pk_bf16(v1.x, v1.y);
      p.w = pk_bf16(v1.z, v1.w);
      *reinterpret_cast<uint4*>(&fS[frow][fcg]) = p;
    }
#pragma unroll
    for (int s = 0; s < 2; ++s) {
      int u = tid + 256 * s;
      if (u < 384) {
        int row = u >> 2, cg = (u & 3) * 8;
        uint4 v = *reinterpret_cast<const uint4*>(qb + (size_t)row * C + c0 + cg);
        *reinterpret_cast<uint4*>(&qS[row][cg]) = v;
      }
    }
    __syncthreads();
    bf16x8 bfr = *reinterpret_cast<const bf16x8*>(&fS[w * 16 + row16][kg * 8]);
#pragma unroll
    for (int i = 0; i < 6; ++i) {
      bf16x8 afr = *reinterpret_cast<const bf16x8*>(&qS[i * 16 + row16][kg * 8]);
      acc[i] = __builtin_amdgcn_mfma_f32_16x16x32_bf16(afr, bfr, acc[i], 0, 0, 0);
    }
    __syncthreads();
  }
  int n = n0 + w * 16 + row16;
#pragma unroll
  for (int i = 0; i < 6; ++i) {
    int rbase = i * 16 + kg * 4;
#pragma unroll
    for (int reg = 0; reg < 4; ++reg) {
      scores[((size_t)b * R + rbase + reg) * NF + n] = acc[i][reg] * SCALE;
    }
  }
}

// ---------------------------------------------------------------------------
// Kernel 3: exact radix-select of top-KSEL per row (ties -> ascending index).
// ---------------------------------------------------------------------------
__global__ __launch_bounds__(256) void ta_select_kernel(
    const float* __restrict__ scores, int* __restrict__ cand) {
  int rr = blockIdx.x;
  int tid = threadIdx.x;
  const float* rowp = scores + (size_t)rr * NF;
  __shared__ uint su[NF];
  __shared__ uint hist[256];
  __shared__ uint cum[256];
  __shared__ uint prefix, above, cgt, ceq;
  __shared__ int gt_list[KSEL];
  __shared__ uint eq_list[64];

  for (int i = tid * 4; i < NF; i += 1024) {
    float4 v = *reinterpret_cast<const float4*>(rowp + i);
    uint u0 = __builtin_bit_cast(uint, v.x);
    uint u1 = __builtin_bit_cast(uint, v.y);
    uint u2 = __builtin_bit_cast(uint, v.z);
    uint u3 = __builtin_bit_cast(uint, v.w);
    su[i + 0] = u0 ^ (uint)(((int)u0 >> 31) | 0x80000000);
    su[i + 1] = u1 ^ (uint)(((int)u1 >> 31) | 0x80000000);
    su[i + 2] = u2 ^ (uint)(((int)u2 >> 31) | 0x80000000);
    su[i + 3] = u3 ^ (uint)(((int)u3 >> 31) | 0x80000000);
  }
  if (tid == 0) { prefix = 0; above = 0; cgt = 0; ceq = 0; }
  __syncthreads();

#pragma unroll 1
  for (int p = 0; p < 4; ++p) {
    int sh = 24 - 8 * p;
    hist[tid] = 0;
    __syncthreads();
    uint pref = prefix;
    uint ab = above;
    for (int i = tid; i < NF; i += 256) {
      uint u = su[i];
      if (p == 0 || (u >> (sh + 8)) == pref)
        atomicAdd(&hist[(u >> sh) & 255], 1u);
    }
    __syncthreads();
    cum[tid] = hist[tid];
    __syncthreads();
#pragma unroll
    for (int off = 1; off < 256; off <<= 1) {
      uint add = (tid + off < 256) ? cum[tid + off] : 0;
      __syncthreads();
      cum[tid] += add;
      __syncthreads();
    }
    uint need = (uint)(KSEL)-ab;
    uint total_ge = cum[tid];
    uint ge_next = (tid < 255) ? cum[tid + 1] : 0;
    if (total_ge >= need && ge_next < need) {
      prefix = (pref << 8) | (uint)tid;
      above = ab + ge_next;
    }
    __syncthreads();
  }

  uint piv = prefix;
  uint ab = above;
  for (int i = tid; i < NF; i += 256) {
    uint u = su[i];
    if (u > piv) {
      uint s = atomicAdd(&cgt, 1u);
      gt_list[s] = i;
    } else if (u == piv) {
      uint s = atomicAdd(&ceq, 1u);
      if (s < 64) eq_list[s] = (uint)i;
    }
  }
  __syncthreads();
  if (tid < (int)ab) cand[(size_t)rr * KSEL + tid] = gt_list[tid];
  uint ne = ceq < 64u ? ceq : 64u;
  if (tid < (int)ne) {
    uint my = eq_list[tid];
    int rk = 0;
    for (uint e = 0; e < ne; ++e) rk += (eq_list[e] < my);
    if (rk < (int)(KSEL - ab)) cand[(size_t)rr * KSEL + ab + rk] = (int)my;
  }
}

// ---------------------------------------------------------------------------
// Kernel 4: exact fp32 rescore of 48 candidates -> true top-32 + softmax.
// ---------------------------------------------------------------------------
__global__ __launch_bounds__(384) void ta_rescore_kernel(
    const float* __restrict__ x, const float* __restrict__ qk_f32,
    const int* __restrict__ cand, float* __restrict__ w_buf,
    int* __restrict__ idx_buf) {
  int rr = blockIdx.x;
  int b = rr / R;
  int tid = threadIdx.x;
  __shared__ float qS[C];
  __shared__ int il[KSEL];
  __shared__ float sv[KSEL];
  __shared__ int rk[KSEL];
  __shared__ float smax, esum;
  qS[tid] = qk_f32[(size_t)rr * C + tid];
  if (tid < KSEL) il[tid] = cand[(size_t)rr * KSEL + tid];
  __syncthreads();
  int k = tid >> 3, j = tid & 7;
  const float* fp = x + ((size_t)b * STOT + T + il[k]) * C + j;
  float s = 0.f;
#pragma unroll 8
  for (int m = 0; m < 48; ++m) s += fp[m * 8] * qS[j + m * 8];
  s += __shfl_down(s, 4);
  s += __shfl_down(s, 2);
  s += __shfl_down(s, 1);
  if (j == 0) sv[k] = s * SCALE;
  __syncthreads();
  if (tid < KSEL) {
    float mys = sv[tid];
    int myn = il[tid];
    int r = 0;
#pragma unroll
    for (int e = 0; e < KSEL; ++e) {
      float se = sv[e];
      r += (se > mys) || (se == mys && il[e] < myn);
    }
    rk[tid] = r;
    if (r == 0) smax = mys;
  }
  __syncthreads();
  float e = 0.f;
  if (tid < KSEL && rk[tid] < TOPK) e = expf(sv[tid] - smax);
  if (tid < 64) {
    float t2 = e;
#pragma unroll
    for (int off = 32; off; off >>= 1) t2 += __shfl_down(t2, off);
    if (tid == 0) esum = t2;
  }
  __syncthreads();
  if (tid < KSEL && rk[tid] < TOPK) {
    w_buf[(size_t)rr * TOPK + rk[tid]] = e / esum;
    idx_buf[(size_t)rr * TOPK + rk[tid]] = il[tid];
  }
}

// ---------------------------------------------------------------------------
// Kernel Z: zero d_out (+ att_buf) with float4 stores.
// ---------------------------------------------------------------------------
__global__ __launch_bounds__(256) void ta_zero_kernel(
    float4* __restrict__ out4, int n_out4, float4* __restrict__ att4, int n_att4) {
  int i = blockIdx.x * 256 + threadIdx.x;
  int stride = gridDim.x * 256;
  float4 z = {0.f, 0.f, 0.f, 0.f};
  for (int j = i; j < n_out4; j += stride) out4[j] = z;
  if (i < n_att4) att4[i] = z;
}

// ---------------------------------------------------------------------------
// Kernel 5: per (b,r,k-half): gather 16 feature rows, v = F . Vw,
// g[k][d] = w_k * F[k][hD+d], atomic-accumulate att[b,t,h,d].
// ---------------------------------------------------------------------------
__global__ __launch_bounds__(256) void ta_gv_kernel(
    const float* __restrict__ x, const float* __restrict__ kv_w,
    const float* __restrict__ w_buf, const int* __restrict__ idx_buf,
    float* __restrict__ g_buf, float* __restrict__ att_buf) {
  constexpr int KH = TOPK / 2;  // 16
  int br = blockIdx.x >> 1, half = blockIdx.x & 1;
  int t = br % T, h = (br / T) % H, b = br / (H * T);
  int tid = threadIdx.x;
  __shared__ float F[KH][C + 4];
  __shared__ float part[8][D];
  __shared__ float wl[KH];
  __shared__ int il[KH];

  if (tid < KH) {
    wl[tid] = w_buf[(size_t)br * TOPK + half * KH + tid];
    il[tid] = idx_buf[(size_t)br * TOPK + half * KH + tid];
  }
  __syncthreads();
  for (int u = tid; u < KH * (C / 4); u += 256) {
    int k = u / (C / 4), e4 = (u % (C / 4)) * 4;
    *reinterpret_cast<float4*>(&F[k][e4]) =
        *reinterpret_cast<const float4*>(x + ((size_t)b * STOT + T + il[k]) * C + e4);
  }
  __syncthreads();

  int d = tid & 31, kg = tid >> 5;
  int k0 = kg, k1 = kg + 8;
  const float* vw = kv_w + C + (size_t)h * D + d;
  float acc0 = 0.f, acc1 = 0.f;
#pragma unroll 4
  for (int c = 0; c < C; c += 4) {
    float w0 = vw[(size_t)(c + 0) * (2 * C)];
    float w1 = vw[(size_t)(c + 1) * (2 * C)];
    float w2 = vw[(size_t)(c + 2) * (2 * C)];
    float w3 = vw[(size_t)(c + 3) * (2 * C)];
    float4 f0 = *reinterpret_cast<const float4*>(&F[k0][c]);
    float4 f1 = *reinterpret_cast<const float4*>(&F[k1][c]);
    acc0 += f0.x * w0 + f0.y * w1 + f0.z * w2 + f0.w * w3;
    acc1 += f1.x * w0 + f1.y * w1 + f1.z * w2 + f1.w * w3;
  }
  size_t gbase = ((size_t)br * TOPK + half * KH) * D;
  g_buf[gbase + (size_t)k0 * D + d] = wl[k0] * F[k0][h * D + d];
  g_buf[gbase + (size_t)k1 * D + d] = wl[k1] * F[k1][h * D + d];
  part[kg][d] = wl[k0] * acc0 + wl[k1] * acc1;
  __syncthreads();
  if (tid < D) {
    float s = 0.f;
#pragma unroll
    for (int g = 0; g < 8; ++g) s += part[g][tid];
    atomicAdd(&att_buf[(((size_t)b * T + t) * H + h) * D + tid], s);
  }
}

// ---------------------------------------------------------------------------
// Kernel 6: scatter. Block = (t,h,b), 384 threads (thread = output col o).
// ---------------------------------------------------------------------------
__global__ __launch_bounds__(384) void ta_scatter_kernel(
    const float* __restrict__ ew, const float* __restrict__ g_buf,
    const float* __restrict__ att_buf, const int* __restrict__ idx_buf,
    float* __restrict__ out) {
  int grp = blockIdx.x >> 2, b = blockIdx.x & 3;
  int t = grp / H, h = grp % H;
  int br = b * R + h * T + t;
  int tid = threadIdx.x;  // = o
  __shared__ float gS[TOPK * D];
  __shared__ float attS[D];
  __shared__ int ilS[TOPK];

  for (int u = tid; u < TOPK * D / 4; u += 384)
    *reinterpret_cast<float4*>(gS + u * 4) =
        *reinterpret_cast<const float4*>(g_buf + (size_t)br * TOPK * D + u * 4);
  if (tid < TOPK) ilS[tid] = idx_buf[(size_t)br * TOPK + tid];
  if (tid < D) attS[tid] = att_buf[(((size_t)b * T + t) * H + h) * D + tid];
  __syncthreads();

  float ewc[D];
  const float* ewt = ew + (size_t)t * C * C + (size_t)h * D * C + tid;
#pragma unroll
  for (int dd = 0; dd < D; ++dd) ewc[dd] = ewt[(size_t)dd * C];

  size_t orow_base = (size_t)b * STOT * C + tid;
#pragma unroll 1
  for (int k = 0; k < TOPK; ++k) {
    float y = 0.f;
#pragma unroll
    for (int d4 = 0; d4 < D; d4 += 4) {
      float4 g4 = *reinterpret_cast<const float4*>(gS + k * D + d4);
      y += g4.x * ewc[d4 + 0] + g4.y * ewc[d4 + 1] +
           g4.z * ewc[d4 + 2] + g4.w * ewc[d4 + 3];
    }
    atomicAdd(&out[orow_base + (size_t)(T + ilS[k]) * C], y);
  }
  {
    float y = 0.f;
#pragma unroll
    for (int d4 = 0; d4 < D; d4 += 4) {
      float4 a4 = *reinterpret_cast<const float4*>(attS + d4);
      y += a4.x * ewc[d4 + 0] + a4.y * ewc[d4 + 1] +
           a4.z * ewc[d4 + 2] + a4.w * ewc[d4 + 3];
    }
    atomicAdd(&out[orow_base + (size_t)t * C], y);
  }
}

// ---------------------------------------------------------------------------
extern "C" void kernel_launch(void* const* d_in, const int* in_sizes, int n_in,
                              void* d_out, int out_size, void* d_ws, size_t ws_size,
                              hipStream_t stream) {
  const float* x = (const float*)d_in[0];
  const float* qs_w = (const float*)d_in[1];
  const float* kv_w = (const float*)d_in[2];
  const float* ew = (const float*)d_in[3];
  float* out = (float*)d_out;

  // ws layout (bytes, 16B-aligned):
  char* p = (char*)d_ws;
  float* qk_f32 = (float*)p;  p += (size_t)B * R * C * 4;         // 589824
  ushort* qk_bf = (ushort*)p; p += (size_t)B * R * C * 2;         // 294912
  int* cand = (int*)p;        p += (size_t)B * R * KSEL * 4;      // 73728
  float* w_buf = (float*)p;   p += (size_t)B * R * TOPK * 4;      // 49152
  int* idx_buf = (int*)p;     p += (size_t)B * R * TOPK * 4;      // 49152
  float* g_buf = (float*)p;   p += (size_t)B * R * TOPK * D * 4;  // 1572864
  float* att_buf = (float*)p; p += (size_t)B * T * H * D * 4;     // 49152
  float* kT = (float*)p;      p += (size_t)C * C * 4;             // 589824
  float* q_part = (float*)p;  // 2*B*T*C floats = 98304 B

  // scores (B*R*NF fp32) staged inside d_out, consumed by select before zero.
  float* scores = out;

  dim3 gt(C / 32, C / 32);
  ta_transpose_kernel<<<gt, 256, 0, stream>>>(kv_w, kT);
  dim3 gq(T, C / 64, 2);
  ta_qproj_kernel<<<gq, 256, 0, stream>>>(x, qs_w, q_part);
  ta_fold_kernel<<<B * H, 384, 0, stream>>>(q_part, kT, qk_f32, qk_bf);
  dim3 g2(NF / 64, B);
  ta_scores_kernel<<<g2, 256, 0, stream>>>(x, qk_bf, scores);
  ta_select_kernel<<<B * R, 256, 0, stream>>>(scores, cand);
  ta_rescore_kernel<<<B * R, 384, 0, stream>>>(x, qk_f32, cand, w_buf, idx_buf);
  ta_zero_kernel<<<2048, 256, 0, stream>>>((float4*)out, out_size / 4,
                                           (float4*)att_buf, B * T * H * D / 4);
  ta_gv_kernel<<<B * R * 2, 256, 0, stream>>>(x, kv_w, w_buf, idx_buf, g_buf, att_buf);
  ta_scatter_kernel<<<T * H * B, 384, 0, stream>>>(ew, g_buf, att_buf, idx_buf, out);
}

// Round 6
// 117.371 us; speedup vs baseline: 1.8939x; 1.0166x over previous
//
#include <hip/hip_runtime.h>
#include <math.h>

#define B 4
#define T 8
#define NF 8192
#define C 384
#define H 12
#define TOPK 32
#define D 32
#define STOT (T + NF)          // 8200
#define R (H * T)              // 96 score rows per batch
#define KSEL 48                // selection margin (bf16 keys -> exact fp32 rescore)
#define SCALE 0.17677669529663687f

typedef unsigned int uint;
typedef unsigned short ushort;
typedef short bf16x8 __attribute__((ext_vector_type(8)));
typedef float f32x4 __attribute__((ext_vector_type(4)));

__device__ __forceinline__ uint pk_bf16(float a, float b) {
  uint ua = __builtin_bit_cast(uint, a);
  uint ub = __builtin_bit_cast(uint, b);
  ua = (ua + 0x7FFFu + ((ua >> 16) & 1u)) >> 16;
  ub = (ub + 0x7FFFu + ((ub >> 16) & 1u)) >> 16;
  return ua | (ub << 16);
}

// order-preserving u16 key from f32 (via bf16 RNE, sign-flip encode)
__device__ __forceinline__ ushort f32_key(float s) {
  uint u = __builtin_bit_cast(uint, s);
  uint ub = (u + 0x7FFFu + ((u >> 16) & 1u)) >> 16;
  ub ^= (ub & 0x8000u) ? 0xFFFFu : 0x8000u;
  return (ushort)ub;
}

// ---------------------------------------------------------------------------
// Kernel 1a: q-projection. grid (T, 6 o-tiles, 2 k-halves), 256 thr =
// 64 o x 4 ks (48 c each). All B batches per thread. q_part[z][b][t][o].
// ---------------------------------------------------------------------------
__global__ __launch_bounds__(256) void ta_qproj_kernel(
    const float* __restrict__ x, const float* __restrict__ qs_w,
    float* __restrict__ q_part) {
  int t = blockIdx.x;
  int o0 = blockIdx.y * 64;
  int z = blockIdx.z;
  int tid = threadIdx.x;
  int o = tid & 63, ks = tid >> 6;
  __shared__ float xs[B][192];
  __shared__ float part[4][B][64];
  if (tid < 192) {
    int b = tid / 48, j4 = (tid % 48) * 4;
    *reinterpret_cast<float4*>(&xs[b][j4]) =
        *reinterpret_cast<const float4*>(x + ((size_t)b * STOT + t) * C + z * 192 + j4);
  }
  __syncthreads();
  float a0 = 0.f, a1 = 0.f, a2 = 0.f, a3 = 0.f;
  const float* w = qs_w + (size_t)t * C * C + (size_t)(z * 192 + ks * 48) * C + o0 + o;
#pragma unroll 8
  for (int c = 0; c < 48; ++c) {
    float wv = w[(size_t)c * C];
    int cj = ks * 48 + c;
    a0 += xs[0][cj] * wv;
    a1 += xs[1][cj] * wv;
    a2 += xs[2][cj] * wv;
    a3 += xs[3][cj] * wv;
  }
  part[ks][0][o] = a0; part[ks][1][o] = a1;
  part[ks][2][o] = a2; part[ks][3][o] = a3;
  __syncthreads();
  {
    int b = tid >> 6, oo = tid & 63;
    float s = part[0][b][oo] + part[1][b][oo] + part[2][b][oo] + part[3][b][oo];
    q_part[(((size_t)z * B + b) * T + t) * C + o0 + oo] = s;
  }
}

// ---------------------------------------------------------------------------
// Kernel 1b: fold k-projection (transpose-free). grid B*H, 384 thr (thread=c).
// Stage kv_w[:, hD:hD+32] into padded LDS (coalesced rows), then
// qk[b,hT+t,c] = sum_d qh[t][d] * kS[c][d].
// ---------------------------------------------------------------------------
__global__ __launch_bounds__(384) void ta_fold_kernel(
    const float* __restrict__ q_part, const float* __restrict__ kv_w,
    float* __restrict__ qk_f32, ushort* __restrict__ qk_bf) {
  int b = blockIdx.x / H, h = blockIdx.x % H;
  int tid = threadIdx.x;
  __shared__ float kS[C][33];   // 50.7 KB, (c+d)%32 bank pattern on read
  __shared__ float qh[T][D];
  if (tid < T * D) {
    int t = tid >> 5, d = tid & 31;
    qh[t][d] = q_part[((size_t)b * T + t) * C + h * D + d] +
               q_part[(((size_t)B + b) * T + t) * C + h * D + d];
  }
  for (int j = tid; j < C * 8; j += 384) {
    int c = j >> 3, d4 = (j & 7) * 4;
    float4 v = *reinterpret_cast<const float4*>(
        kv_w + (size_t)c * (2 * C) + h * D + d4);
    kS[c][d4 + 0] = v.x; kS[c][d4 + 1] = v.y;
    kS[c][d4 + 2] = v.z; kS[c][d4 + 3] = v.w;
  }
  __syncthreads();
  float acc[T] = {0.f, 0.f, 0.f, 0.f, 0.f, 0.f, 0.f, 0.f};
#pragma unroll
  for (int d = 0; d < D; ++d) {
    float kv = kS[tid][d];
#pragma unroll
    for (int t = 0; t < T; ++t) acc[t] += qh[t][d] * kv;
  }
#pragma unroll
  for (int t = 0; t < T; ++t) {
    size_t off = ((size_t)b * R + (size_t)h * T + t) * C + tid;
    float a = acc[t];
    qk_f32[off] = a;
    uint ua = __builtin_bit_cast(uint, a);
    qk_bf[off] = (ushort)((ua + 0x7FFFu + ((ua >> 16) & 1u)) >> 16);
  }
}

// ---------------------------------------------------------------------------
// Kernel 2: bf16 MFMA scores -> u16 sort-keys. Block = 64 n x 96 r, 4 waves.
// ---------------------------------------------------------------------------
__global__ __launch_bounds__(256) void ta_scores_kernel(
    const float* __restrict__ x, const ushort* __restrict__ qk_bf,
    ushort* __restrict__ keys) {
  int b = blockIdx.y;
  int n0 = blockIdx.x * 64;
  int tid = threadIdx.x;
  int lane = tid & 63, w = tid >> 6;
  int row16 = lane & 15, kg = lane >> 4;
  __shared__ ushort fS[64][72];
  __shared__ ushort qS[96][72];
  f32x4 acc[6];
#pragma unroll
  for (int i = 0; i < 6; ++i) acc[i] = (f32x4){0.f, 0.f, 0.f, 0.f};

  const float* xb = x + ((size_t)b * STOT + T + n0) * C;
  const ushort* qb = qk_bf + (size_t)b * R * C;

  int frow = tid >> 2, fcg = (tid & 3) * 8;

#pragma unroll 1
  for (int c0 = 0; c0 < C; c0 += 32) {
    {
      const float* src = xb + (size_t)frow * C + c0 + fcg;
      float4 v0 = *reinterpret_cast<const float4*>(src);
      float4 v1 = *reinterpret_cast<const float4*>(src + 4);
      uint4 p;
      p.x = pk_bf16(v0.x, v0.y);
      p.y = pk_bf16(v0.z, v0.w);
      p.z = pk_bf16(v1.x, v1.y);
      p.w = pk_bf16(v1.z, v1.w);
      *reinterpret_cast<uint4*>(&fS[frow][fcg]) = p;
    }
#pragma unroll
    for (int s = 0; s < 2; ++s) {
      int u = tid + 256 * s;
      if (u < 384) {
        int row = u >> 2, cg = (u & 3) * 8;
        uint4 v = *reinterpret_cast<const uint4*>(qb + (size_t)row * C + c0 + cg);
        *reinterpret_cast<uint4*>(&qS[row][cg]) = v;
      }
    }
    __syncthreads();
    bf16x8 bfr = *reinterpret_cast<const bf16x8*>(&fS[w * 16 + row16][kg * 8]);
#pragma unroll
    for (int i = 0; i < 6; ++i) {
      bf16x8 afr = *reinterpret_cast<const bf16x8*>(&qS[i * 16 + row16][kg * 8]);
      acc[i] = __builtin_amdgcn_mfma_f32_16x16x32_bf16(afr, bfr, acc[i], 0, 0, 0);
    }
    __syncthreads();
  }
  int n = n0 + w * 16 + row16;
#pragma unroll
  for (int i = 0; i < 6; ++i) {
    int rbase = i * 16 + kg * 4;
#pragma unroll
    for (int reg = 0; reg < 4; ++reg) {
      keys[((size_t)b * R + rbase + reg) * NF + n] = f32_key(acc[i][reg] * SCALE);
    }
  }
}

// ---------------------------------------------------------------------------
// Kernel 3: fused select (2-pass radix on u16 keys) + exact fp32 rescore +
// softmax. One block per score row, 384 threads.
// ---------------------------------------------------------------------------
__global__ __launch_bounds__(384) void ta_selres_kernel(
    const ushort* __restrict__ keys, const float* __restrict__ x,
    const float* __restrict__ qk_f32, float* __restrict__ w_buf,
    int* __restrict__ idx_buf) {
  int rr = blockIdx.x;
  int b = rr / R;
  int tid = threadIdx.x;
  __shared__ __align__(16) ushort su[NF];   // 16 KB
  __shared__ uint hist[256], cum[256];
  __shared__ uint sh_prefix, sh_above, cgt, ceq;
  __shared__ int gt_list[KSEL];
  __shared__ int eq_list[128];
  __shared__ int il[KSEL];
  __shared__ float sv[KSEL];
  __shared__ int rkS[KSEL];
  __shared__ float qS[C];
  __shared__ float smax, esum;

  {
    const uint4* src = reinterpret_cast<const uint4*>(keys + (size_t)rr * NF);
    uint4* dst = reinterpret_cast<uint4*>(su);
    for (int j = tid; j < NF / 8; j += 384) dst[j] = src[j];
  }
  qS[tid] = qk_f32[(size_t)rr * C + tid];
  if (tid < 256) hist[tid] = 0;
  if (tid == 0) { cgt = 0; ceq = 0; }
  __syncthreads();

  // pass 1: top byte
  for (int i = tid; i < NF; i += 384) atomicAdd(&hist[su[i] >> 8], 1u);
  __syncthreads();
  if (tid < 256) cum[tid] = hist[tid];
  __syncthreads();
#pragma unroll
  for (int off = 1; off < 256; off <<= 1) {
    uint add = (tid < 256 - off) ? cum[tid + off] : 0u;
    __syncthreads();
    if (tid < 256) cum[tid] += add;
    __syncthreads();
  }
  if (tid < 256) {
    uint ge = cum[tid], gn = (tid < 255) ? cum[tid + 1] : 0u;
    if (ge >= (uint)KSEL && gn < (uint)KSEL) { sh_prefix = (uint)tid; sh_above = gn; }
  }
  __syncthreads();
  uint pref1 = sh_prefix, ab1 = sh_above;
  if (tid < 256) hist[tid] = 0;
  __syncthreads();
  // pass 2: low byte among prefix matches
  for (int i = tid; i < NF; i += 384) {
    uint u = su[i];
    if ((u >> 8) == pref1) atomicAdd(&hist[u & 255], 1u);
  }
  __syncthreads();
  if (tid < 256) cum[tid] = hist[tid];
  __syncthreads();
#pragma unroll
  for (int off = 1; off < 256; off <<= 1) {
    uint add = (tid < 256 - off) ? cum[tid + off] : 0u;
    __syncthreads();
    if (tid < 256) cum[tid] += add;
    __syncthreads();
  }
  {
    uint need2 = (uint)KSEL - ab1;
    if (tid < 256) {
      uint ge = cum[tid], gn = (tid < 255) ? cum[tid + 1] : 0u;
      if (ge >= need2 && gn < need2) {
        sh_prefix = (pref1 << 8) | (uint)tid;
        sh_above = ab1 + gn;
      }
    }
  }
  __syncthreads();
  uint piv = sh_prefix, ab = sh_above;   // ab = #(key > piv) < KSEL
  for (int i = tid; i < NF; i += 384) {
    uint u = su[i];
    if (u > piv) {
      uint s = atomicAdd(&cgt, 1u);
      gt_list[s] = i;
    } else if (u == piv) {
      uint s = atomicAdd(&ceq, 1u);
      if (s < 128) eq_list[s] = i;
    }
  }
  __syncthreads();
  if (tid < (int)ab) il[tid] = gt_list[tid];
  {
    uint ne = ceq < 128u ? ceq : 128u;
    if (tid < (int)ne) {
      int my = eq_list[tid];
      int r2 = 0;
      for (uint e = 0; e < ne; ++e) r2 += (eq_list[e] < my);
      if (r2 < (int)((uint)KSEL - ab)) il[ab + r2] = my;
    }
  }
  __syncthreads();

  // exact fp32 rescore of the 48 candidates (8 threads per candidate)
  int k = tid >> 3, j = tid & 7;
  const float* fp = x + ((size_t)b * STOT + T + il[k]) * C + j;
  float s = 0.f;
#pragma unroll 8
  for (int m = 0; m < 48; ++m) s += fp[m * 8] * qS[j + m * 8];
  s += __shfl_down(s, 4);
  s += __shfl_down(s, 2);
  s += __shfl_down(s, 1);
  if (j == 0) sv[k] = s * SCALE;
  __syncthreads();
  if (tid < KSEL) {
    float mys = sv[tid];
    int myn = il[tid];
    int r = 0;
#pragma unroll
    for (int e = 0; e < KSEL; ++e) {
      float se = sv[e];
      r += (se > mys) || (se == mys && il[e] < myn);
    }
    rkS[tid] = r;
    if (r == 0) smax = mys;
  }
  __syncthreads();
  float e = 0.f;
  if (tid < KSEL && rkS[tid] < TOPK) e = expf(sv[tid] - smax);
  if (tid < 64) {
    float t2 = e;
#pragma unroll
    for (int off = 32; off; off >>= 1) t2 += __shfl_down(t2, off);
    if (tid == 0) esum = t2;
  }
  __syncthreads();
  if (tid < KSEL && rkS[tid] < TOPK) {
    w_buf[(size_t)rr * TOPK + rkS[tid]] = e / esum;
    idx_buf[(size_t)rr * TOPK + rkS[tid]] = il[tid];
  }
}

// ---------------------------------------------------------------------------
// Kernel Z: zero d_out with float4 stores.
// ---------------------------------------------------------------------------
__global__ __launch_bounds__(256) void ta_zero_kernel(
    float4* __restrict__ out4, int n4) {
  int i = blockIdx.x * 256 + threadIdx.x;
  int stride = gridDim.x * 256;
  float4 z = {0.f, 0.f, 0.f, 0.f};
  for (int j = i; j < n4; j += stride) out4[j] = z;
}

// ---------------------------------------------------------------------------
// Kernel 4: fused epilogue. grid = 384 (br), 384 thr.
// Phases: gather F[32][C] -> v-compute (kv_w loaded once per c, broadcast)
// -> att -> register-ew scatter (33 atomic rows).
// ---------------------------------------------------------------------------
__global__ __launch_bounds__(384) void ta_epilogue_kernel(
    const float* __restrict__ x, const float* __restrict__ kv_w,
    const float* __restrict__ ew, const float* __restrict__ w_buf,
    const int* __restrict__ idx_buf, float* __restrict__ out) {
  int br = blockIdx.x;
  int t = br % T, h = (br / T) % H, b = br / R;
  int tid = threadIdx.x;
  __shared__ float F[TOPK][C + 4];       // 49.7 KB
  __shared__ float vS[TOPK][33];         // 4.2 KB
  __shared__ __align__(16) float att[D];
  __shared__ float wl[TOPK];
  __shared__ int il[TOPK];

  if (tid < TOPK) {
    wl[tid] = w_buf[(size_t)br * TOPK + tid];
    il[tid] = idx_buf[(size_t)br * TOPK + tid];
  }
  __syncthreads();
  for (int u = tid; u < TOPK * (C / 4); u += 384) {
    int k = u / (C / 4), e4 = (u % (C / 4)) * 4;
    *reinterpret_cast<float4*>(&F[k][e4]) =
        *reinterpret_cast<const float4*>(x + ((size_t)b * STOT + T + il[k]) * C + e4);
  }
  __syncthreads();
  {
    int d = tid & 31, kg = tid >> 5;  // kg 0..11
    int k0 = kg, k1 = kg + 12, k2 = (kg < 8) ? kg + 24 : kg;
    const float* vw = kv_w + C + (size_t)h * D + d;
    float a0 = 0.f, a1 = 0.f, a2 = 0.f;
#pragma unroll 4
    for (int c = 0; c < C; ++c) {
      float wv = vw[(size_t)c * (2 * C)];
      a0 += F[k0][c] * wv;
      a1 += F[k1][c] * wv;
      a2 += F[k2][c] * wv;
    }
    vS[k0][d] = a0;
    vS[k1][d] = a1;
    if (kg < 8) vS[k2][d] = a2;
  }
  __syncthreads();
  if (tid < D) {
    float a = 0.f;
#pragma unroll
    for (int kk = 0; kk < TOPK; ++kk) a += wl[kk] * vS[kk][tid];
    att[tid] = a;
  }
  __syncthreads();

  // scatter: thread = output column o
  float ewc[D];
  const float* ewt = ew + (size_t)t * C * C + (size_t)h * D * C + tid;
#pragma unroll
  for (int dd = 0; dd < D; ++dd) ewc[dd] = ewt[(size_t)dd * C];
  size_t obase = (size_t)b * STOT * C + tid;
#pragma unroll 1
  for (int kk = 0; kk < TOPK; ++kk) {
    float y = 0.f;
#pragma unroll
    for (int d4 = 0; d4 < D; d4 += 4) {
      float4 f4 = *reinterpret_cast<const float4*>(&F[kk][h * D + d4]);
      y += f4.x * ewc[d4] + f4.y * ewc[d4 + 1] +
           f4.z * ewc[d4 + 2] + f4.w * ewc[d4 + 3];
    }
    atomicAdd(&out[obase + (size_t)(T + il[kk]) * C], wl[kk] * y);
  }
  {
    float y = 0.f;
#pragma unroll
    for (int d4 = 0; d4 < D; d4 += 4) {
      float4 a4 = *reinterpret_cast<const float4*>(att + d4);
      y += a4.x * ewc[d4] + a4.y * ewc[d4 + 1] +
           a4.z * ewc[d4 + 2] + a4.w * ewc[d4 + 3];
    }
    atomicAdd(&out[obase + (size_t)t * C], y);
  }
}

// ---------------------------------------------------------------------------
extern "C" void kernel_launch(void* const* d_in, const int* in_sizes, int n_in,
                              void* d_out, int out_size, void* d_ws, size_t ws_size,
                              hipStream_t stream) {
  const float* x = (const float*)d_in[0];
  const float* qs_w = (const float*)d_in[1];
  const float* kv_w = (const float*)d_in[2];
  const float* ew = (const float*)d_in[3];
  float* out = (float*)d_out;

  // ws layout (bytes, 16B-aligned):
  char* p = (char*)d_ws;
  float* qk_f32 = (float*)p;  p += (size_t)B * R * C * 4;        // 589824
  ushort* qk_bf = (ushort*)p; p += (size_t)B * R * C * 2;        // 294912
  ushort* keys = (ushort*)p;  p += (size_t)B * R * NF * 2;       // 6291456
  float* w_buf = (float*)p;   p += (size_t)B * R * TOPK * 4;     // 49152
  int* idx_buf = (int*)p;     p += (size_t)B * R * TOPK * 4;     // 49152
  float* q_part = (float*)p;  // 2*B*T*C floats = 98304 B

  dim3 gq(T, C / 64, 2);
  ta_qproj_kernel<<<gq, 256, 0, stream>>>(x, qs_w, q_part);
  ta_fold_kernel<<<B * H, 384, 0, stream>>>(q_part, kv_w, qk_f32, qk_bf);
  dim3 g2(NF / 64, B);
  ta_scores_kernel<<<g2, 256, 0, stream>>>(x, qk_bf, keys);
  ta_selres_kernel<<<B * R, 384, 0, stream>>>(keys, x, qk_f32, w_buf, idx_buf);
  ta_zero_kernel<<<2048, 256, 0, stream>>>((float4*)out, out_size / 4);
  ta_epilogue_kernel<<<B * R, 384, 0, stream>>>(x, kv_w, ew, w_buf, idx_buf, out);
}

// Round 7
// 97.686 us; speedup vs baseline: 2.2755x; 1.2015x over previous
//
#include <hip/hip_runtime.h>
#include <math.h>

#define B 4
#define T 8
#define NF 8192
#define C 384
#define H 12
#define TOPK 32
#define D 32
#define STOT (T + NF)          // 8200
#define R (H * T)              // 96 score rows per batch
#define KSEL 48                // selection margin (bf16 keys -> exact fp32 rescore)
#define SCALE 0.17677669529663687f

typedef unsigned int uint;
typedef unsigned short ushort;
typedef short bf16x8 __attribute__((ext_vector_type(8)));
typedef float f32x4 __attribute__((ext_vector_type(4)));

__device__ __forceinline__ uint pk_bf16(float a, float b) {
  uint ua = __builtin_bit_cast(uint, a);
  uint ub = __builtin_bit_cast(uint, b);
  ua = (ua + 0x7FFFu + ((ua >> 16) & 1u)) >> 16;
  ub = (ub + 0x7FFFu + ((ub >> 16) & 1u)) >> 16;
  return ua | (ub << 16);
}

// order-preserving u16 key from f32 (via bf16 RNE, sign-flip encode)
__device__ __forceinline__ ushort f32_key(float s) {
  uint u = __builtin_bit_cast(uint, s);
  uint ub = (u + 0x7FFFu + ((u >> 16) & 1u)) >> 16;
  ub ^= (ub & 0x8000u) ? 0xFFFFu : 0x8000u;
  return (ushort)ub;
}

// ---------------------------------------------------------------------------
// Kernel 1a: q-projection. grid (T, 6 o-tiles, 2 k-halves), 256 thr.
// ---------------------------------------------------------------------------
__global__ __launch_bounds__(256) void ta_qproj_kernel(
    const float* __restrict__ x, const float* __restrict__ qs_w,
    float* __restrict__ q_part) {
  int t = blockIdx.x;
  int o0 = blockIdx.y * 64;
  int z = blockIdx.z;
  int tid = threadIdx.x;
  int o = tid & 63, ks = tid >> 6;
  __shared__ float xs[B][192];
  __shared__ float part[4][B][64];
  if (tid < 192) {
    int b = tid / 48, j4 = (tid % 48) * 4;
    *reinterpret_cast<float4*>(&xs[b][j4]) =
        *reinterpret_cast<const float4*>(x + ((size_t)b * STOT + t) * C + z * 192 + j4);
  }
  __syncthreads();
  float a0 = 0.f, a1 = 0.f, a2 = 0.f, a3 = 0.f;
  const float* w = qs_w + (size_t)t * C * C + (size_t)(z * 192 + ks * 48) * C + o0 + o;
#pragma unroll 8
  for (int c = 0; c < 48; ++c) {
    float wv = w[(size_t)c * C];
    int cj = ks * 48 + c;
    a0 += xs[0][cj] * wv;
    a1 += xs[1][cj] * wv;
    a2 += xs[2][cj] * wv;
    a3 += xs[3][cj] * wv;
  }
  part[ks][0][o] = a0; part[ks][1][o] = a1;
  part[ks][2][o] = a2; part[ks][3][o] = a3;
  __syncthreads();
  {
    int b = tid >> 6, oo = tid & 63;
    float s = part[0][b][oo] + part[1][b][oo] + part[2][b][oo] + part[3][b][oo];
    q_part[(((size_t)z * B + b) * T + t) * C + o0 + oo] = s;
  }
}

// ---------------------------------------------------------------------------
// Kernel 1b: fold k-projection. grid B*H, 384 thr (thread = c).
// ---------------------------------------------------------------------------
__global__ __launch_bounds__(384) void ta_fold_kernel(
    const float* __restrict__ q_part, const float* __restrict__ kv_w,
    float* __restrict__ qk_f32, ushort* __restrict__ qk_bf) {
  int b = blockIdx.x / H, h = blockIdx.x % H;
  int tid = threadIdx.x;
  __shared__ float kS[C][33];
  __shared__ float qh[T][D];
  if (tid < T * D) {
    int t = tid >> 5, d = tid & 31;
    qh[t][d] = q_part[((size_t)b * T + t) * C + h * D + d] +
               q_part[(((size_t)B + b) * T + t) * C + h * D + d];
  }
  for (int j = tid; j < C * 8; j += 384) {
    int c = j >> 3, d4 = (j & 7) * 4;
    float4 v = *reinterpret_cast<const float4*>(
        kv_w + (size_t)c * (2 * C) + h * D + d4);
    kS[c][d4 + 0] = v.x; kS[c][d4 + 1] = v.y;
    kS[c][d4 + 2] = v.z; kS[c][d4 + 3] = v.w;
  }
  __syncthreads();
  float acc[T] = {0.f, 0.f, 0.f, 0.f, 0.f, 0.f, 0.f, 0.f};
#pragma unroll
  for (int d = 0; d < D; ++d) {
    float kv = kS[tid][d];
#pragma unroll
    for (int t = 0; t < T; ++t) acc[t] += qh[t][d] * kv;
  }
#pragma unroll
  for (int t = 0; t < T; ++t) {
    size_t off = ((size_t)b * R + (size_t)h * T + t) * C + tid;
    float a = acc[t];
    qk_f32[off] = a;
    uint ua = __builtin_bit_cast(uint, a);
    qk_bf[off] = (ushort)((ua + 0x7FFFu + ((ua >> 16) & 1u)) >> 16);
  }
}

// ---------------------------------------------------------------------------
// Kernel 2: bf16 MFMA scores -> u16 sort-keys. Block = 64 n x 96 r, 4 waves.
// ---------------------------------------------------------------------------
__global__ __launch_bounds__(256) void ta_scores_kernel(
    const float* __restrict__ x, const ushort* __restrict__ qk_bf,
    ushort* __restrict__ keys) {
  int b = blockIdx.y;
  int n0 = blockIdx.x * 64;
  int tid = threadIdx.x;
  int lane = tid & 63, w = tid >> 6;
  int row16 = lane & 15, kg = lane >> 4;
  __shared__ ushort fS[64][72];
  __shared__ ushort qS[96][72];
  f32x4 acc[6];
#pragma unroll
  for (int i = 0; i < 6; ++i) acc[i] = (f32x4){0.f, 0.f, 0.f, 0.f};

  const float* xb = x + ((size_t)b * STOT + T + n0) * C;
  const ushort* qb = qk_bf + (size_t)b * R * C;

  int frow = tid >> 2, fcg = (tid & 3) * 8;

#pragma unroll 1
  for (int c0 = 0; c0 < C; c0 += 32) {
    {
      const float* src = xb + (size_t)frow * C + c0 + fcg;
      float4 v0 = *reinterpret_cast<const float4*>(src);
      float4 v1 = *reinterpret_cast<const float4*>(src + 4);
      uint4 p;
      p.x = pk_bf16(v0.x, v0.y);
      p.y = pk_bf16(v0.z, v0.w);
      p.z = pk_bf16(v1.x, v1.y);
      p.w = pk_bf16(v1.z, v1.w);
      *reinterpret_cast<uint4*>(&fS[frow][fcg]) = p;
    }
#pragma unroll
    for (int s = 0; s < 2; ++s) {
      int u = tid + 256 * s;
      if (u < 384) {
        int row = u >> 2, cg = (u & 3) * 8;
        uint4 v = *reinterpret_cast<const uint4*>(qb + (size_t)row * C + c0 + cg);
        *reinterpret_cast<uint4*>(&qS[row][cg]) = v;
      }
    }
    __syncthreads();
    bf16x8 bfr = *reinterpret_cast<const bf16x8*>(&fS[w * 16 + row16][kg * 8]);
#pragma unroll
    for (int i = 0; i < 6; ++i) {
      bf16x8 afr = *reinterpret_cast<const bf16x8*>(&qS[i * 16 + row16][kg * 8]);
      acc[i] = __builtin_amdgcn_mfma_f32_16x16x32_bf16(afr, bfr, acc[i], 0, 0, 0);
    }
    __syncthreads();
  }
  int n = n0 + w * 16 + row16;
#pragma unroll
  for (int i = 0; i < 6; ++i) {
    int rbase = i * 16 + kg * 4;
#pragma unroll
    for (int reg = 0; reg < 4; ++reg) {
      keys[((size_t)b * R + rbase + reg) * NF + n] = f32_key(acc[i][reg] * SCALE);
    }
  }
}

// ---------------------------------------------------------------------------
// Kernel 3: fused select (2-pass radix on u16 keys) + exact fp32 rescore +
// softmax. One block per score row, 384 threads.
// ---------------------------------------------------------------------------
__global__ __launch_bounds__(384) void ta_selres_kernel(
    const ushort* __restrict__ keys, const float* __restrict__ x,
    const float* __restrict__ qk_f32, float* __restrict__ w_buf,
    int* __restrict__ idx_buf) {
  int rr = blockIdx.x;
  int b = rr / R;
  int tid = threadIdx.x;
  __shared__ __align__(16) ushort su[NF];   // 16 KB
  __shared__ uint hist[256], cum[256];
  __shared__ uint sh_prefix, sh_above, cgt, ceq;
  __shared__ int gt_list[KSEL];
  __shared__ int eq_list[128];
  __shared__ int il[KSEL];
  __shared__ float sv[KSEL];
  __shared__ int rkS[KSEL];
  __shared__ float qS[C];
  __shared__ float smax, esum;

  {
    const uint4* src = reinterpret_cast<const uint4*>(keys + (size_t)rr * NF);
    uint4* dst = reinterpret_cast<uint4*>(su);
    for (int j = tid; j < NF / 8; j += 384) dst[j] = src[j];
  }
  qS[tid] = qk_f32[(size_t)rr * C + tid];
  if (tid < 256) hist[tid] = 0;
  if (tid == 0) { cgt = 0; ceq = 0; }
  __syncthreads();

  for (int i = tid; i < NF; i += 384) atomicAdd(&hist[su[i] >> 8], 1u);
  __syncthreads();
  if (tid < 256) cum[tid] = hist[tid];
  __syncthreads();
#pragma unroll
  for (int off = 1; off < 256; off <<= 1) {
    uint add = (tid < 256 - off) ? cum[tid + off] : 0u;
    __syncthreads();
    if (tid < 256) cum[tid] += add;
    __syncthreads();
  }
  if (tid < 256) {
    uint ge = cum[tid], gn = (tid < 255) ? cum[tid + 1] : 0u;
    if (ge >= (uint)KSEL && gn < (uint)KSEL) { sh_prefix = (uint)tid; sh_above = gn; }
  }
  __syncthreads();
  uint pref1 = sh_prefix, ab1 = sh_above;
  if (tid < 256) hist[tid] = 0;
  __syncthreads();
  for (int i = tid; i < NF; i += 384) {
    uint u = su[i];
    if ((u >> 8) == pref1) atomicAdd(&hist[u & 255], 1u);
  }
  __syncthreads();
  if (tid < 256) cum[tid] = hist[tid];
  __syncthreads();
#pragma unroll
  for (int off = 1; off < 256; off <<= 1) {
    uint add = (tid < 256 - off) ? cum[tid + off] : 0u;
    __syncthreads();
    if (tid < 256) cum[tid] += add;
    __syncthreads();
  }
  {
    uint need2 = (uint)KSEL - ab1;
    if (tid < 256) {
      uint ge = cum[tid], gn = (tid < 255) ? cum[tid + 1] : 0u;
      if (ge >= need2 && gn < need2) {
        sh_prefix = (pref1 << 8) | (uint)tid;
        sh_above = ab1 + gn;
      }
    }
  }
  __syncthreads();
  uint piv = sh_prefix, ab = sh_above;
  for (int i = tid; i < NF; i += 384) {
    uint u = su[i];
    if (u > piv) {
      uint s = atomicAdd(&cgt, 1u);
      gt_list[s] = i;
    } else if (u == piv) {
      uint s = atomicAdd(&ceq, 1u);
      if (s < 128) eq_list[s] = i;
    }
  }
  __syncthreads();
  if (tid < (int)ab) il[tid] = gt_list[tid];
  {
    uint ne = ceq < 128u ? ceq : 128u;
    if (tid < (int)ne) {
      int my = eq_list[tid];
      int r2 = 0;
      for (uint e = 0; e < ne; ++e) r2 += (eq_list[e] < my);
      if (r2 < (int)((uint)KSEL - ab)) il[ab + r2] = my;
    }
  }
  __syncthreads();

  int k = tid >> 3, j = tid & 7;
  const float* fp = x + ((size_t)b * STOT + T + il[k]) * C + j;
  float s = 0.f;
#pragma unroll 8
  for (int m = 0; m < 48; ++m) s += fp[m * 8] * qS[j + m * 8];
  s += __shfl_down(s, 4);
  s += __shfl_down(s, 2);
  s += __shfl_down(s, 1);
  if (j == 0) sv[k] = s * SCALE;
  __syncthreads();
  if (tid < KSEL) {
    float mys = sv[tid];
    int myn = il[tid];
    int r = 0;
#pragma unroll
    for (int e = 0; e < KSEL; ++e) {
      float se = sv[e];
      r += (se > mys) || (se == mys && il[e] < myn);
    }
    rkS[tid] = r;
    if (r == 0) smax = mys;
  }
  __syncthreads();
  float e = 0.f;
  if (tid < KSEL && rkS[tid] < TOPK) e = expf(sv[tid] - smax);
  if (tid < 64) {
    float t2 = e;
#pragma unroll
    for (int off = 32; off; off >>= 1) t2 += __shfl_down(t2, off);
    if (tid == 0) esum = t2;
  }
  __syncthreads();
  if (tid < KSEL && rkS[tid] < TOPK) {
    w_buf[(size_t)rr * TOPK + rkS[tid]] = e / esum;
    idx_buf[(size_t)rr * TOPK + rkS[tid]] = il[tid];
  }
}

// ---------------------------------------------------------------------------
// Kernel Z: zero d_out with float4 stores.
// ---------------------------------------------------------------------------
__global__ __launch_bounds__(256) void ta_zero_kernel(
    float4* __restrict__ out4, int n4) {
  int i = blockIdx.x * 256 + threadIdx.x;
  int stride = gridDim.x * 256;
  float4 z = {0.f, 0.f, 0.f, 0.f};
  for (int j = i; j < n4; j += stride) out4[j] = z;
}

// ---------------------------------------------------------------------------
// Kernel 4: gv with chunked LDS staging. Block per br (384), 256 thr =
// 32 k x 8 dg. c in 4 chunks of 96: stage Fc (gathered feat) + Vc (kv_w
// v-slice) to LDS, pure-LDS inner loop. att computed in-block (no atomics).
// ---------------------------------------------------------------------------
__global__ __launch_bounds__(256) void ta_gv_kernel(
    const float* __restrict__ x, const float* __restrict__ kv_w,
    const float* __restrict__ w_buf, const int* __restrict__ idx_buf,
    float* __restrict__ g_buf, float* __restrict__ att_buf) {
  int br = blockIdx.x;
  int h = (br / T) % H, b = br / R;
  int tid = threadIdx.x;
  int k = tid >> 3, dg = tid & 7;
  __shared__ float Fc[TOPK][100];   // 12.8 KB (bank stride 4)
  __shared__ float Vc[96][36];      // 13.8 KB (bank stride 4)
  __shared__ float vS[TOPK][36];    // 4.6 KB
  __shared__ float wl[TOPK];
  __shared__ int il[TOPK];

  if (tid < TOPK) {
    wl[tid] = w_buf[(size_t)br * TOPK + tid];
    il[tid] = idx_buf[(size_t)br * TOPK + tid];
  }
  __syncthreads();
  float4 acc = {0.f, 0.f, 0.f, 0.f};
  int hc = (h * D) / 96;   // chunk containing [hD, hD+32)
#pragma unroll 1
  for (int ch = 0; ch < 4; ++ch) {
    int c0 = ch * 96;
    if (ch) __syncthreads();
    // stage Fc: 32 rows x 24 float4
#pragma unroll
    for (int s = 0; s < 3; ++s) {
      int u = tid + 256 * s;
      int kr = u / 24, c4 = (u % 24) * 4;
      *reinterpret_cast<float4*>(&Fc[kr][c4]) =
          *reinterpret_cast<const float4*>(
              x + ((size_t)b * STOT + T + il[kr]) * C + c0 + c4);
    }
    // stage Vc: 96 rows x 8 float4
#pragma unroll
    for (int s = 0; s < 3; ++s) {
      int u = tid + 256 * s;
      int cr = u >> 3, d4 = (u & 7) * 4;
      *reinterpret_cast<float4*>(&Vc[cr][d4]) =
          *reinterpret_cast<const float4*>(
              kv_w + (size_t)(c0 + cr) * (2 * C) + C + h * D + d4);
    }
    __syncthreads();
    if (ch == hc) {  // g extraction: g[k][d] = wl[k] * F[k][hD+d]
      int off = h * D - c0;
      float4 f = *reinterpret_cast<const float4*>(&Fc[k][off + 4 * dg]);
      float wk = wl[k];
      float4 g = {wk * f.x, wk * f.y, wk * f.z, wk * f.w};
      *reinterpret_cast<float4*>(
          &g_buf[((size_t)br * TOPK + k) * D + 4 * dg]) = g;
    }
#pragma unroll 4
    for (int c = 0; c < 96; c += 4) {
      float4 f4 = *reinterpret_cast<const float4*>(&Fc[k][c]);
      float4 v0 = *reinterpret_cast<const float4*>(&Vc[c + 0][4 * dg]);
      float4 v1 = *reinterpret_cast<const float4*>(&Vc[c + 1][4 * dg]);
      float4 v2 = *reinterpret_cast<const float4*>(&Vc[c + 2][4 * dg]);
      float4 v3 = *reinterpret_cast<const float4*>(&Vc[c + 3][4 * dg]);
      acc.x += f4.x * v0.x + f4.y * v1.x + f4.z * v2.x + f4.w * v3.x;
      acc.y += f4.x * v0.y + f4.y * v1.y + f4.z * v2.y + f4.w * v3.y;
      acc.z += f4.x * v0.z + f4.y * v1.z + f4.z * v2.z + f4.w * v3.z;
      acc.w += f4.x * v0.w + f4.y * v1.w + f4.z * v2.w + f4.w * v3.w;
    }
  }
  *reinterpret_cast<float4*>(&vS[k][4 * dg]) = acc;
  __syncthreads();
  if (tid < D) {
    float a = 0.f;
#pragma unroll
    for (int kk = 0; kk < TOPK; ++kk) a += wl[kk] * vS[kk][tid];
    att_buf[(size_t)br * D + tid] = a;
  }
}

// ---------------------------------------------------------------------------
// Kernel 5: scatter. Block = (t,h,b), 384 thr (thread = output col o),
// ew columns register-cached; 33 atomic rows per thread.
// ---------------------------------------------------------------------------
__global__ __launch_bounds__(384) void ta_scatter_kernel(
    const float* __restrict__ ew, const float* __restrict__ g_buf,
    const float* __restrict__ att_buf, const int* __restrict__ idx_buf,
    float* __restrict__ out) {
  int grp = blockIdx.x >> 2, b = blockIdx.x & 3;
  int t = grp / H, h = grp % H;
  int br = b * R + h * T + t;
  int tid = threadIdx.x;  // = o
  __shared__ float gS[TOPK * D];
  __shared__ __align__(16) float attS[D];
  __shared__ int ilS[TOPK];

  for (int u = tid; u < TOPK * D / 4; u += 384)
    *reinterpret_cast<float4*>(gS + u * 4) =
        *reinterpret_cast<const float4*>(g_buf + (size_t)br * TOPK * D + u * 4);
  if (tid < TOPK) ilS[tid] = idx_buf[(size_t)br * TOPK + tid];
  if (tid < D) attS[tid] = att_buf[(size_t)br * D + tid];
  __syncthreads();

  float ewc[D];
  const float* ewt = ew + (size_t)t * C * C + (size_t)h * D * C + tid;
#pragma unroll
  for (int dd = 0; dd < D; ++dd) ewc[dd] = ewt[(size_t)dd * C];

  size_t obase = (size_t)b * STOT * C + tid;
#pragma unroll 1
  for (int kk = 0; kk < TOPK; ++kk) {
    float y = 0.f;
#pragma unroll
    for (int d4 = 0; d4 < D; d4 += 4) {
      float4 g4 = *reinterpret_cast<const float4*>(gS + kk * D + d4);
      y += g4.x * ewc[d4] + g4.y * ewc[d4 + 1] +
           g4.z * ewc[d4 + 2] + g4.w * ewc[d4 + 3];
    }
    atomicAdd(&out[obase + (size_t)(T + ilS[kk]) * C], y);
  }
  {
    float y = 0.f;
#pragma unroll
    for (int d4 = 0; d4 < D; d4 += 4) {
      float4 a4 = *reinterpret_cast<const float4*>(attS + d4);
      y += a4.x * ewc[d4] + a4.y * ewc[d4 + 1] +
           a4.z * ewc[d4 + 2] + a4.w * ewc[d4 + 3];
    }
    atomicAdd(&out[obase + (size_t)t * C], y);
  }
}

// ---------------------------------------------------------------------------
extern "C" void kernel_launch(void* const* d_in, const int* in_sizes, int n_in,
                              void* d_out, int out_size, void* d_ws, size_t ws_size,
                              hipStream_t stream) {
  const float* x = (const float*)d_in[0];
  const float* qs_w = (const float*)d_in[1];
  const float* kv_w = (const float*)d_in[2];
  const float* ew = (const float*)d_in[3];
  float* out = (float*)d_out;

  char* p = (char*)d_ws;
  float* qk_f32 = (float*)p;  p += (size_t)B * R * C * 4;        // 589824
  ushort* qk_bf = (ushort*)p; p += (size_t)B * R * C * 2;        // 294912
  ushort* keys = (ushort*)p;  p += (size_t)B * R * NF * 2;       // 6291456
  float* w_buf = (float*)p;   p += (size_t)B * R * TOPK * 4;     // 49152
  int* idx_buf = (int*)p;     p += (size_t)B * R * TOPK * 4;     // 49152
  float* g_buf = (float*)p;   p += (size_t)B * R * TOPK * D * 4; // 1572864
  float* att_buf = (float*)p; p += (size_t)B * R * D * 4;        // 49152
  float* q_part = (float*)p;  // 2*B*T*C floats

  dim3 gq(T, C / 64, 2);
  ta_qproj_kernel<<<gq, 256, 0, stream>>>(x, qs_w, q_part);
  ta_fold_kernel<<<B * H, 384, 0, stream>>>(q_part, kv_w, qk_f32, qk_bf);
  dim3 g2(NF / 64, B);
  ta_scores_kernel<<<g2, 256, 0, stream>>>(x, qk_bf, keys);
  ta_selres_kernel<<<B * R, 384, 0, stream>>>(keys, x, qk_f32, w_buf, idx_buf);
  ta_zero_kernel<<<2048, 256, 0, stream>>>((float4*)out, out_size / 4);
  ta_gv_kernel<<<B * R, 256, 0, stream>>>(x, kv_w, w_buf, idx_buf, g_buf, att_buf);
  ta_scatter_kernel<<<T * H * B, 384, 0, stream>>>(ew, g_buf, att_buf, idx_buf, out);
}

// Round 8
// 88.770 us; speedup vs baseline: 2.5041x; 1.1004x over previous
//
#include <hip/hip_runtime.h>
#include <hip/hip_bf16.h>
#include <math.h>

#define B 4
#define T 8
#define NF 8192
#define C 384
#define H 12
#define TOPK 32
#define D 32
#define STOT (T + NF)          // 8200
#define R (H * T)              // 96 score rows per batch
#define KSEL 48                // selection margin (bf16 keys -> exact fp32 rescore)
#define SCALE 0.17677669529663687f

typedef unsigned int uint;
typedef unsigned short ushort;
typedef short bf16x8 __attribute__((ext_vector_type(8)));
typedef float f32x4 __attribute__((ext_vector_type(4)));

__device__ __forceinline__ ushort bf16u(float a) {
  return __builtin_bit_cast(ushort, __float2bfloat16(a));
}

// order-preserving u16 key from f32 (bf16 RNE, sign-flip encode)
__device__ __forceinline__ ushort f32_key(float s) {
  uint kb = bf16u(s);
  kb ^= (kb & 0x8000u) ? 0xFFFFu : 0x8000u;
  return (ushort)kb;
}

// ---------------------------------------------------------------------------
// Kernel 1a: q-projection. grid (T, 6 o-tiles, 2 k-halves), 256 thr.
// ---------------------------------------------------------------------------
__global__ __launch_bounds__(256) void ta_qproj_kernel(
    const float* __restrict__ x, const float* __restrict__ qs_w,
    float* __restrict__ q_part) {
  int t = blockIdx.x;
  int o0 = blockIdx.y * 64;
  int z = blockIdx.z;
  int tid = threadIdx.x;
  int o = tid & 63, ks = tid >> 6;
  __shared__ float xs[B][192];
  __shared__ float part[4][B][64];
  if (tid < 192) {
    int b = tid / 48, j4 = (tid % 48) * 4;
    *reinterpret_cast<float4*>(&xs[b][j4]) =
        *reinterpret_cast<const float4*>(x + ((size_t)b * STOT + t) * C + z * 192 + j4);
  }
  __syncthreads();
  float a0 = 0.f, a1 = 0.f, a2 = 0.f, a3 = 0.f;
  const float* w = qs_w + (size_t)t * C * C + (size_t)(z * 192 + ks * 48) * C + o0 + o;
#pragma unroll 8
  for (int c = 0; c < 48; ++c) {
    float wv = w[(size_t)c * C];
    int cj = ks * 48 + c;
    a0 += xs[0][cj] * wv;
    a1 += xs[1][cj] * wv;
    a2 += xs[2][cj] * wv;
    a3 += xs[3][cj] * wv;
  }
  part[ks][0][o] = a0; part[ks][1][o] = a1;
  part[ks][2][o] = a2; part[ks][3][o] = a3;
  __syncthreads();
  {
    int b = tid >> 6, oo = tid & 63;
    float s = part[0][b][oo] + part[1][b][oo] + part[2][b][oo] + part[3][b][oo];
    q_part[(((size_t)z * B + b) * T + t) * C + o0 + oo] = s;
  }
}

// ---------------------------------------------------------------------------
// Kernel 1b: fold k-projection. grid B*H, 384 thr (thread = c).
// ---------------------------------------------------------------------------
__global__ __launch_bounds__(384) void ta_fold_kernel(
    const float* __restrict__ q_part, const float* __restrict__ kv_w,
    float* __restrict__ qk_f32, ushort* __restrict__ qk_bf) {
  int b = blockIdx.x / H, h = blockIdx.x % H;
  int tid = threadIdx.x;
  __shared__ float kS[C][33];
  __shared__ float qh[T][D];
  if (tid < T * D) {
    int t = tid >> 5, d = tid & 31;
    qh[t][d] = q_part[((size_t)b * T + t) * C + h * D + d] +
               q_part[(((size_t)B + b) * T + t) * C + h * D + d];
  }
  for (int j = tid; j < C * 8; j += 384) {
    int c = j >> 3, d4 = (j & 7) * 4;
    float4 v = *reinterpret_cast<const float4*>(
        kv_w + (size_t)c * (2 * C) + h * D + d4);
    kS[c][d4 + 0] = v.x; kS[c][d4 + 1] = v.y;
    kS[c][d4 + 2] = v.z; kS[c][d4 + 3] = v.w;
  }
  __syncthreads();
  float acc[T] = {0.f, 0.f, 0.f, 0.f, 0.f, 0.f, 0.f, 0.f};
#pragma unroll
  for (int d = 0; d < D; ++d) {
    float kv = kS[tid][d];
#pragma unroll
    for (int t = 0; t < T; ++t) acc[t] += qh[t][d] * kv;
  }
#pragma unroll
  for (int t = 0; t < T; ++t) {
    size_t off = ((size_t)b * R + (size_t)h * T + t) * C + tid;
    float a = acc[t];
    qk_f32[off] = a;
    qk_bf[off] = bf16u(a);
  }
}

// ---------------------------------------------------------------------------
// Kernel 2: bf16 MFMA scores -> u16 sort-keys. Block = 64 n x 96 r, 4 waves.
// ---------------------------------------------------------------------------
__global__ __launch_bounds__(256) void ta_scores_kernel(
    const float* __restrict__ x, const ushort* __restrict__ qk_bf,
    ushort* __restrict__ keys) {
  int b = blockIdx.y;
  int n0 = blockIdx.x * 64;
  int tid = threadIdx.x;
  int lane = tid & 63, w = tid >> 6;
  int row16 = lane & 15, kg = lane >> 4;
  __shared__ ushort fS[64][72];
  __shared__ ushort qS[96][72];
  f32x4 acc[6];
#pragma unroll
  for (int i = 0; i < 6; ++i) acc[i] = (f32x4){0.f, 0.f, 0.f, 0.f};

  const float* xb = x + ((size_t)b * STOT + T + n0) * C;
  const ushort* qb = qk_bf + (size_t)b * R * C;

  int frow = tid >> 2, fcg = (tid & 3) * 8;

#pragma unroll 1
  for (int c0 = 0; c0 < C; c0 += 32) {
    {
      const float* src = xb + (size_t)frow * C + c0 + fcg;
      float4 v0 = *reinterpret_cast<const float4*>(src);
      float4 v1 = *reinterpret_cast<const float4*>(src + 4);
      uint4 p;
      p.x = (uint)bf16u(v0.x) | ((uint)bf16u(v0.y) << 16);
      p.y = (uint)bf16u(v0.z) | ((uint)bf16u(v0.w) << 16);
      p.z = (uint)bf16u(v1.x) | ((uint)bf16u(v1.y) << 16);
      p.w = (uint)bf16u(v1.z) | ((uint)bf16u(v1.w) << 16);
      *reinterpret_cast<uint4*>(&fS[frow][fcg]) = p;
    }
#pragma unroll
    for (int s = 0; s < 2; ++s) {
      int u = tid + 256 * s;
      if (u < 384) {
        int row = u >> 2, cg = (u & 3) * 8;
        uint4 v = *reinterpret_cast<const uint4*>(qb + (size_t)row * C + c0 + cg);
        *reinterpret_cast<uint4*>(&qS[row][cg]) = v;
      }
    }
    __syncthreads();
    bf16x8 bfr = *reinterpret_cast<const bf16x8*>(&fS[w * 16 + row16][kg * 8]);
#pragma unroll
    for (int i = 0; i < 6; ++i) {
      bf16x8 afr = *reinterpret_cast<const bf16x8*>(&qS[i * 16 + row16][kg * 8]);
      acc[i] = __builtin_amdgcn_mfma_f32_16x16x32_bf16(afr, bfr, acc[i], 0, 0, 0);
    }
    __syncthreads();
  }
  int n = n0 + w * 16 + row16;
#pragma unroll
  for (int i = 0; i < 6; ++i) {
    int rbase = i * 16 + kg * 4;
#pragma unroll
    for (int reg = 0; reg < 4; ++reg) {
      keys[((size_t)b * R + rbase + reg) * NF + n] = f32_key(acc[i][reg] * SCALE);
    }
  }
}

// ---------------------------------------------------------------------------
// Kernel 3: fused select (2-pass radix, wave-scan) + exact fp32 rescore +
// softmax + d_out zeroing. One block per score row, 384 threads, 6 waves.
// ---------------------------------------------------------------------------
__global__ __launch_bounds__(384) void ta_selres_kernel(
    const ushort* __restrict__ keys, const float* __restrict__ x,
    const float* __restrict__ qk_f32, float* __restrict__ w_buf,
    int* __restrict__ idx_buf, float4* __restrict__ out4) {
  int rr = blockIdx.x;
  int b = rr / R;
  int tid = threadIdx.x;
  int lane = tid & 63, wvi = tid >> 6;   // 6 waves
  __shared__ __align__(16) ushort su[NF];   // 16 KB
  __shared__ uint histW[6][256];            // 6 KB (wave-privatized)
  __shared__ uint sh_prefix, sh_above, cgt, ceq;
  __shared__ int gt_list[KSEL];
  __shared__ int eq_list[128];
  __shared__ int il[KSEL];
  __shared__ float sv[KSEL];
  __shared__ int rkS[KSEL];
  __shared__ float qS[C];
  __shared__ float smax, esum;

  {
    const uint4* src = reinterpret_cast<const uint4*>(keys + (size_t)rr * NF);
    uint4* dst = reinterpret_cast<uint4*>(su);
    for (int j = tid; j < NF / 8; j += 384) dst[j] = src[j];
  }
  // zero this block's slice of d_out (fire-and-forget; drains under selection)
  {
    float4 z = {0.f, 0.f, 0.f, 0.f};
    float4* dst = out4 + (size_t)rr * (B * STOT * C / 4 / (B * R));
    for (int j = tid; j < B * STOT * C / 4 / (B * R); j += 384) dst[j] = z;
  }
  qS[tid] = qk_f32[(size_t)rr * C + tid];
  for (int i = tid; i < 6 * 256; i += 384) (&histW[0][0])[i] = 0;
  if (tid == 0) { cgt = 0; ceq = 0; }
  __syncthreads();

  // ---- pass 1: top byte ----
  for (int i = tid; i < NF; i += 384) atomicAdd(&histW[wvi][su[i] >> 8], 1u);
  __syncthreads();
  if (tid < 64) {
    uint h0 = 0, h1 = 0, h2 = 0, h3 = 0;
#pragma unroll
    for (int wq = 0; wq < 6; ++wq) {
      h0 += histW[wq][4 * lane + 0];
      h1 += histW[wq][4 * lane + 1];
      h2 += histW[wq][4 * lane + 2];
      h3 += histW[wq][4 * lane + 3];
    }
    uint lsum = h0 + h1 + h2 + h3;
    uint suf = lsum;
#pragma unroll
    for (int off = 1; off < 64; off <<= 1) {
      uint o = __shfl_down(suf, off);
      if (lane + off < 64) suf += o;
    }
    uint gn3 = suf - lsum;          // suffix of lanes > lane
    uint ge3 = gn3 + h3;
    uint ge2 = ge3 + h2;
    uint ge1 = ge2 + h1;
    uint ge0 = ge1 + h0;
    const uint need = KSEL;
    if (ge0 >= need && ge1 < need) { sh_prefix = 4 * lane + 0; sh_above = ge1; }
    if (ge1 >= need && ge2 < need) { sh_prefix = 4 * lane + 1; sh_above = ge2; }
    if (ge2 >= need && ge3 < need) { sh_prefix = 4 * lane + 2; sh_above = ge3; }
    if (ge3 >= need && gn3 < need) { sh_prefix = 4 * lane + 3; sh_above = gn3; }
  }
  __syncthreads();
  uint pref1 = sh_prefix, ab1 = sh_above;
  for (int i = tid; i < 6 * 256; i += 384) (&histW[0][0])[i] = 0;
  __syncthreads();
  // ---- pass 2: low byte among prefix matches ----
  for (int i = tid; i < NF; i += 384) {
    uint u = su[i];
    if ((u >> 8) == pref1) atomicAdd(&histW[wvi][u & 255], 1u);
  }
  __syncthreads();
  if (tid < 64) {
    uint h0 = 0, h1 = 0, h2 = 0, h3 = 0;
#pragma unroll
    for (int wq = 0; wq < 6; ++wq) {
      h0 += histW[wq][4 * lane + 0];
      h1 += histW[wq][4 * lane + 1];
      h2 += histW[wq][4 * lane + 2];
      h3 += histW[wq][4 * lane + 3];
    }
    uint lsum = h0 + h1 + h2 + h3;
    uint suf = lsum;
#pragma unroll
    for (int off = 1; off < 64; off <<= 1) {
      uint o = __shfl_down(suf, off);
      if (lane + off < 64) suf += o;
    }
    uint gn3 = suf - lsum;
    uint ge3 = gn3 + h3;
    uint ge2 = ge3 + h2;
    uint ge1 = ge2 + h1;
    uint ge0 = ge1 + h0;
    const uint need = (uint)KSEL - ab1;
    if (ge0 >= need && ge1 < need) { sh_prefix = (pref1 << 8) | (4 * lane + 0); sh_above = ab1 + ge1; }
    if (ge1 >= need && ge2 < need) { sh_prefix = (pref1 << 8) | (4 * lane + 1); sh_above = ab1 + ge2; }
    if (ge2 >= need && ge3 < need) { sh_prefix = (pref1 << 8) | (4 * lane + 2); sh_above = ab1 + ge3; }
    if (ge3 >= need && gn3 < need) { sh_prefix = (pref1 << 8) | (4 * lane + 3); sh_above = ab1 + gn3; }
  }
  __syncthreads();
  uint piv = sh_prefix, ab = sh_above;   // ab = #(key > piv) < KSEL
  for (int i = tid; i < NF; i += 384) {
    uint u = su[i];
    if (u > piv) {
      uint s = atomicAdd(&cgt, 1u);
      gt_list[s] = i;
    } else if (u == piv) {
      uint s = atomicAdd(&ceq, 1u);
      if (s < 128) eq_list[s] = i;
    }
  }
  __syncthreads();
  if (tid < (int)ab) il[tid] = gt_list[tid];
  {
    uint ne = ceq < 128u ? ceq : 128u;
    if (tid < (int)ne) {
      int my = eq_list[tid];
      int r2 = 0;
      for (uint e = 0; e < ne; ++e) r2 += (eq_list[e] < my);
      if (r2 < (int)((uint)KSEL - ab)) il[ab + r2] = my;
    }
  }
  __syncthreads();

  // exact fp32 rescore of the 48 candidates (8 threads per candidate)
  int k = tid >> 3, j = tid & 7;
  const float* fp = x + ((size_t)b * STOT + T + il[k]) * C + j;
  float s = 0.f;
#pragma unroll 8
  for (int m = 0; m < 48; ++m) s += fp[m * 8] * qS[j + m * 8];
  s += __shfl_down(s, 4);
  s += __shfl_down(s, 2);
  s += __shfl_down(s, 1);
  if (j == 0) sv[k] = s * SCALE;
  __syncthreads();
  if (tid < KSEL) {
    float mys = sv[tid];
    int myn = il[tid];
    int r = 0;
#pragma unroll
    for (int e = 0; e < KSEL; ++e) {
      float se = sv[e];
      r += (se > mys) || (se == mys && il[e] < myn);
    }
    rkS[tid] = r;
    if (r == 0) smax = mys;
  }
  __syncthreads();
  float e = 0.f;
  if (tid < KSEL && rkS[tid] < TOPK) e = expf(sv[tid] - smax);
  if (tid < 64) {
    float t2 = e;
#pragma unroll
    for (int off = 32; off; off >>= 1) t2 += __shfl_down(t2, off);
    if (tid == 0) esum = t2;
  }
  __syncthreads();
  if (tid < KSEL && rkS[tid] < TOPK) {
    w_buf[(size_t)rr * TOPK + rkS[tid]] = e / esum;
    idx_buf[(size_t)rr * TOPK + rkS[tid]] = il[tid];
  }
}

// ---------------------------------------------------------------------------
// Kernel 4: fused gv + scatter. Block per br (384), 256 thr.
// gv: 32 k x 8 dg, c in 4 chunks of 96 (Fc/Vc LDS-staged, pure-LDS inner).
// g, att stay in LDS. scatter: 256 thr cover 384 cols (2nd col for tid<128),
// ew register-cached, 33 atomic rows.
// ---------------------------------------------------------------------------
__global__ __launch_bounds__(256) void ta_gvscatter_kernel(
    const float* __restrict__ x, const float* __restrict__ kv_w,
    const float* __restrict__ ew, const float* __restrict__ w_buf,
    const int* __restrict__ idx_buf, float* __restrict__ out) {
  int br = blockIdx.x;
  int t = br % T, h = (br / T) % H, b = br / R;
  int tid = threadIdx.x;
  int k = tid >> 3, dg = tid & 7;
  __shared__ float Fc[TOPK][100];   // 12.8 KB
  __shared__ float Vc[96][36];      // 13.8 KB
  __shared__ float vS[TOPK][36];    // 4.6 KB
  __shared__ float gS[TOPK][36];    // 4.6 KB (w-folded gathered feature slice)
  __shared__ __align__(16) float attS[D];
  __shared__ float wl[TOPK];
  __shared__ int il[TOPK];

  if (tid < TOPK) {
    wl[tid] = w_buf[(size_t)br * TOPK + tid];
    il[tid] = idx_buf[(size_t)br * TOPK + tid];
  }
  __syncthreads();
  float4 acc = {0.f, 0.f, 0.f, 0.f};
  int hc = (h * D) / 96;   // chunk containing [hD, hD+32)
#pragma unroll 1
  for (int ch = 0; ch < 4; ++ch) {
    int c0 = ch * 96;
    if (ch) __syncthreads();
#pragma unroll
    for (int s = 0; s < 3; ++s) {
      int u = tid + 256 * s;
      int kr = u / 24, c4 = (u % 24) * 4;
      *reinterpret_cast<float4*>(&Fc[kr][c4]) =
          *reinterpret_cast<const float4*>(
              x + ((size_t)b * STOT + T + il[kr]) * C + c0 + c4);
    }
#pragma unroll
    for (int s = 0; s < 3; ++s) {
      int u = tid + 256 * s;
      int cr = u >> 3, d4 = (u & 7) * 4;
      *reinterpret_cast<float4*>(&Vc[cr][d4]) =
          *reinterpret_cast<const float4*>(
              kv_w + (size_t)(c0 + cr) * (2 * C) + C + h * D + d4);
    }
    __syncthreads();
    if (ch == hc) {  // g[k][d] = wl[k] * F[k][hD+d]
      int off = h * D - c0;
      float4 f = *reinterpret_cast<const float4*>(&Fc[k][off + 4 * dg]);
      float wk = wl[k];
      float4 g = {wk * f.x, wk * f.y, wk * f.z, wk * f.w};
      *reinterpret_cast<float4*>(&gS[k][4 * dg]) = g;
    }
#pragma unroll 4
    for (int c = 0; c < 96; c += 4) {
      float4 f4 = *reinterpret_cast<const float4*>(&Fc[k][c]);
      float4 v0 = *reinterpret_cast<const float4*>(&Vc[c + 0][4 * dg]);
      float4 v1 = *reinterpret_cast<const float4*>(&Vc[c + 1][4 * dg]);
      float4 v2 = *reinterpret_cast<const float4*>(&Vc[c + 2][4 * dg]);
      float4 v3 = *reinterpret_cast<const float4*>(&Vc[c + 3][4 * dg]);
      acc.x += f4.x * v0.x + f4.y * v1.x + f4.z * v2.x + f4.w * v3.x;
      acc.y += f4.x * v0.y + f4.y * v1.y + f4.z * v2.y + f4.w * v3.y;
      acc.z += f4.x * v0.z + f4.y * v1.z + f4.z * v2.z + f4.w * v3.z;
      acc.w += f4.x * v0.w + f4.y * v1.w + f4.z * v2.w + f4.w * v3.w;
    }
  }
  *reinterpret_cast<float4*>(&vS[k][4 * dg]) = acc;
  __syncthreads();
  if (tid < D) {
    float a = 0.f;
#pragma unroll
    for (int kk = 0; kk < TOPK; ++kk) a += wl[kk] * vS[kk][tid];
    attS[tid] = a;
  }
  __syncthreads();

  // ---- scatter phase: columns o0 = tid, o1 = tid + 256 (tid < 128) ----
  float ewc0[D], ewc1[D];
  const float* ewt = ew + (size_t)t * C * C + (size_t)h * D * C;
#pragma unroll
  for (int dd = 0; dd < D; ++dd) {
    ewc0[dd] = ewt[(size_t)dd * C + tid];
    ewc1[dd] = (tid < 128) ? ewt[(size_t)dd * C + tid + 256] : 0.f;
  }
  size_t obase = (size_t)b * STOT * C;
#pragma unroll 1
  for (int kk = 0; kk < TOPK; ++kk) {
    float y0 = 0.f, y1 = 0.f;
#pragma unroll
    for (int d4 = 0; d4 < D; d4 += 4) {
      float4 g4 = *reinterpret_cast<const float4*>(&gS[kk][d4]);
      y0 += g4.x * ewc0[d4] + g4.y * ewc0[d4 + 1] +
            g4.z * ewc0[d4 + 2] + g4.w * ewc0[d4 + 3];
      y1 += g4.x * ewc1[d4] + g4.y * ewc1[d4 + 1] +
            g4.z * ewc1[d4 + 2] + g4.w * ewc1[d4 + 3];
    }
    size_t row = obase + (size_t)(T + il[kk]) * C;
    atomicAdd(&out[row + tid], y0);
    if (tid < 128) atomicAdd(&out[row + tid + 256], y1);
  }
  {
    float y0 = 0.f, y1 = 0.f;
#pragma unroll
    for (int d4 = 0; d4 < D; d4 += 4) {
      float4 a4 = *reinterpret_cast<const float4*>(attS + d4);
      y0 += a4.x * ewc0[d4] + a4.y * ewc0[d4 + 1] +
            a4.z * ewc0[d4 + 2] + a4.w * ewc0[d4 + 3];
      y1 += a4.x * ewc1[d4] + a4.y * ewc1[d4 + 1] +
            a4.z * ewc1[d4 + 2] + a4.w * ewc1[d4 + 3];
    }
    size_t row = obase + (size_t)t * C;
    atomicAdd(&out[row + tid], y0);
    if (tid < 128) atomicAdd(&out[row + tid + 256], y1);
  }
}

// ---------------------------------------------------------------------------
extern "C" void kernel_launch(void* const* d_in, const int* in_sizes, int n_in,
                              void* d_out, int out_size, void* d_ws, size_t ws_size,
                              hipStream_t stream) {
  const float* x = (const float*)d_in[0];
  const float* qs_w = (const float*)d_in[1];
  const float* kv_w = (const float*)d_in[2];
  const float* ew = (const float*)d_in[3];
  float* out = (float*)d_out;

  char* p = (char*)d_ws;
  float* qk_f32 = (float*)p;  p += (size_t)B * R * C * 4;        // 589824
  ushort* qk_bf = (ushort*)p; p += (size_t)B * R * C * 2;        // 294912
  ushort* keys = (ushort*)p;  p += (size_t)B * R * NF * 2;       // 6291456
  float* w_buf = (float*)p;   p += (size_t)B * R * TOPK * 4;     // 49152
  int* idx_buf = (int*)p;     p += (size_t)B * R * TOPK * 4;     // 49152
  float* q_part = (float*)p;  // 2*B*T*C floats

  dim3 gq(T, C / 64, 2);
  ta_qproj_kernel<<<gq, 256, 0, stream>>>(x, qs_w, q_part);
  ta_fold_kernel<<<B * H, 384, 0, stream>>>(q_part, kv_w, qk_f32, qk_bf);
  dim3 g2(NF / 64, B);
  ta_scores_kernel<<<g2, 256, 0, stream>>>(x, qk_bf, keys);
  ta_selres_kernel<<<B * R, 384, 0, stream>>>(keys, x, qk_f32, w_buf, idx_buf,
                                              (float4*)out);
  ta_gvscatter_kernel<<<B * R, 256, 0, stream>>>(x, kv_w, ew, w_buf, idx_buf, out);
}